// Round 1
// baseline (309.352 us; speedup 1.0000x reference)
//
#include <hip/hip_runtime.h>

// Problem constants
#define B_   2
#define N_   2048
#define C_   1024
#define H_   16
#define D_   64
#define BH_  (B_*H_)      // 32
#define NDH  (N_*D_)      // 131072 elems per (b,h) plane
#define M1   (B_*N_)      // 4096 rows

typedef __attribute__((ext_vector_type(4))) float    f32x4;
typedef __attribute__((ext_vector_type(8))) _Float16 f16x8;
typedef __attribute__((ext_vector_type(4))) _Float16 f16x4;

// ---------------- fp32 -> fp16 convert ----------------
__global__ void k_cvt16(const float* __restrict__ in, _Float16* __restrict__ out, int n4) {
  int i = blockIdx.x * blockDim.x + threadIdx.x;
  if (i >= n4) return;
  float4 v = ((const float4*)in)[i];
  f16x4 o;
  o.x = (_Float16)v.x; o.y = (_Float16)v.y; o.z = (_Float16)v.z; o.w = (_Float16)v.w;
  ((f16x4*)out)[i] = o;
}

// ------------- fp32 [R][Cc] -> fp16 [Cc][R] transpose-convert -------------
__global__ __launch_bounds__(256) void k_transpose16(const float* __restrict__ in,
                                                     _Float16* __restrict__ out,
                                                     int R, int Cc) {
  __shared__ _Float16 t[64][68];   // +4 pad breaks bank conflicts
  int c0 = blockIdx.x * 64, r0 = blockIdx.y * 64;
  int tid = threadIdx.x;
  int cq = tid & 15, rq = tid >> 4;
#pragma unroll
  for (int i = 0; i < 4; ++i) {
    int r = rq + i * 16;
    float4 v = *(const float4*)(in + (size_t)(r0 + r) * Cc + c0 + cq * 4);
    t[r][cq*4+0] = (_Float16)v.x;
    t[r][cq*4+1] = (_Float16)v.y;
    t[r][cq*4+2] = (_Float16)v.z;
    t[r][cq*4+3] = (_Float16)v.w;
  }
  __syncthreads();
#pragma unroll
  for (int i = 0; i < 4; ++i) {
    int c = rq + i * 16;
    f16x4 o;
    o.x = t[cq*4+0][c];
    o.y = t[cq*4+1][c];
    o.z = t[cq*4+2][c];
    o.w = t[cq*4+3][c];
    *(f16x4*)(out + (size_t)(c0 + c) * R + r0 + cq * 4) = o;
  }
}

// ---------------- GEMM1: qkv = x @ w_qkv, scatter epilogue ----------------
// A [4096][1024] fp16 row-major; BT [3072][1024] fp16 (= w_qkv^T)
__global__ __launch_bounds__(256) void k_gemm_qkv(const _Float16* __restrict__ A,
                                                  const _Float16* __restrict__ BT,
                                                  float* __restrict__ qf,
                                                  float* __restrict__ kf,
                                                  _Float16* __restrict__ vh) {
  __shared__ __align__(16) _Float16 As[128 * 40];
  __shared__ __align__(16) _Float16 Bs[128 * 40];
  const int tid = threadIdx.x, lane = tid & 63, wave = tid >> 6;
  const int wm = wave >> 1, wn = wave & 1;
  const int mcol = lane & 15, quad = lane >> 4;
  const int m0 = blockIdx.x * 128, n0 = blockIdx.y * 128;
  f32x4 acc[4][4] = {};
  for (int k0 = 0; k0 < 1024; k0 += 32) {
#pragma unroll
    for (int r = 0; r < 2; ++r) {
      int chunk = tid + r * 256;
      int row = chunk >> 2, kc = chunk & 3;
      *(int4*)&As[row * 40 + kc * 8] = *(const int4*)(A  + (size_t)(m0 + row) * 1024 + k0 + kc * 8);
      *(int4*)&Bs[row * 40 + kc * 8] = *(const int4*)(BT + (size_t)(n0 + row) * 1024 + k0 + kc * 8);
    }
    __syncthreads();
    f16x8 af[4], bf[4];
#pragma unroll
    for (int tm = 0; tm < 4; ++tm)
      af[tm] = *(const f16x8*)&As[(wm * 64 + tm * 16 + mcol) * 40 + quad * 8];
#pragma unroll
    for (int tn = 0; tn < 4; ++tn)
      bf[tn] = *(const f16x8*)&Bs[(wn * 64 + tn * 16 + mcol) * 40 + quad * 8];
#pragma unroll
    for (int tm = 0; tm < 4; ++tm)
#pragma unroll
      for (int tn = 0; tn < 4; ++tn)
        acc[tm][tn] = __builtin_amdgcn_mfma_f32_16x16x32_f16(af[tm], bf[tn], acc[tm][tn], 0, 0, 0);
    __syncthreads();
  }
  // epilogue: col sections 0=q,1=k,2=v (uniform per block since n0 % 128 == 0)
  const int sec = n0 >> 10;
  if (sec < 2) {
    float* dst = sec ? kf : qf;
#pragma unroll
    for (int tm = 0; tm < 4; ++tm)
#pragma unroll
      for (int tn = 0; tn < 4; ++tn)
#pragma unroll
        for (int reg = 0; reg < 4; ++reg) {
          int row = m0 + wm * 64 + tm * 16 + quad * 4 + reg;
          int col = n0 + wn * 64 + tn * 16 + mcol;
          int cc = col & 1023, h = cc >> 6, d = cc & 63;
          int b = row >> 11, n = row & 2047;
          dst[((size_t)(b * 16 + h) * 2048 + n) * 64 + d] = acc[tm][tn][reg];
        }
  } else {
    // v: store transposed [B,H,D,N] as fp16, 4 consecutive n per lane -> 8B stores
#pragma unroll
    for (int tm = 0; tm < 4; ++tm)
#pragma unroll
      for (int tn = 0; tn < 4; ++tn) {
        int rowb = m0 + wm * 64 + tm * 16 + quad * 4;
        int col = n0 + wn * 64 + tn * 16 + mcol;
        int cc = col & 1023, h = cc >> 6, d = cc & 63;
        int b = rowb >> 11, n = rowb & 2047;
        f16x4 o;
        o.x = (_Float16)acc[tm][tn][0];
        o.y = (_Float16)acc[tm][tn][1];
        o.z = (_Float16)acc[tm][tn][2];
        o.w = (_Float16)acc[tm][tn][3];
        *(f16x4*)&vh[((size_t)(b * 16 + h) * 64 + d) * 2048 + n] = o;
      }
  }
}

// ---------------- per-(b,h) amax of q and k ----------------
__global__ __launch_bounds__(256) void k_amax(const float* __restrict__ qf,
                                              const float* __restrict__ kf,
                                              float* __restrict__ amax) {
  int b = blockIdx.x;  // 0..31 = q planes, 32..63 = k planes
  const float* src = (b < 32 ? qf : kf) + (size_t)(b & 31) * NDH;
  int tid = threadIdx.x;
  float mx = 0.f;
  for (int i = tid; i < NDH / 4; i += 256) {
    float4 v = ((const float4*)src)[i];
    mx = fmaxf(mx, fmaxf(fmaxf(fabsf(v.x), fabsf(v.y)), fmaxf(fabsf(v.z), fabsf(v.w))));
  }
#pragma unroll
  for (int off = 32; off; off >>= 1) mx = fmaxf(mx, __shfl_xor(mx, off, 64));
  __shared__ float red[4];
  if ((tid & 63) == 0) red[tid >> 6] = mx;
  __syncthreads();
  if (tid == 0) amax[b] = fmaxf(fmaxf(red[0], red[1]), fmaxf(red[2], red[3]));
}

// ---------------- fp8 e4m3 quantize (RNE, matches XLA) ----------------
__global__ __launch_bounds__(256) void k_quant(const float* __restrict__ qf,
                                               const float* __restrict__ kf,
                                               const float* __restrict__ amax,
                                               char* __restrict__ q8,
                                               char* __restrict__ k8) {
  int blk = blockIdx.x;
  int which = blk >> 11;          // 0 = q, 1 = k
  int idx = blk & 2047;
  int bh = idx >> 6, chunk = idx & 63;
  const float* src = (which ? kf : qf) + (size_t)bh * NDH + chunk * 2048;
  char* dst = (which ? k8 : q8) + (size_t)bh * NDH + chunk * 2048;
  float s = 448.f / fmaxf(amax[which * 32 + bh], 1e-12f);
  int t = threadIdx.x;
  float4 a = ((const float4*)(src + t * 8))[0];
  float4 c = ((const float4*)(src + t * 8))[1];
  int lo = 0, hi = 0;
  lo = __builtin_amdgcn_cvt_pk_fp8_f32(a.x * s, a.y * s, lo, false);
  lo = __builtin_amdgcn_cvt_pk_fp8_f32(a.z * s, a.w * s, lo, true);
  hi = __builtin_amdgcn_cvt_pk_fp8_f32(c.x * s, c.y * s, hi, false);
  hi = __builtin_amdgcn_cvt_pk_fp8_f32(c.z * s, c.w * s, hi, true);
  int2 o; o.x = lo; o.y = hi;
  *(int2*)(dst + t * 8) = o;
}

// ---------------- flash causal attention ----------------
// grid: (N/64 q-tiles, B*H). Each wave owns 16 q-rows. S via fp8 MFMA, PV via f16 MFMA.
__global__ __launch_bounds__(256) void k_flash(const char* __restrict__ q8,
                                               const char* __restrict__ k8,
                                               const _Float16* __restrict__ vh,
                                               const float* __restrict__ amax,
                                               _Float16* __restrict__ attn) {
  __shared__ __align__(16) char     K8s[64 * 80];     // [key][d], +16B pad
  __shared__ __align__(16) _Float16 Vt[64 * 72];      // [d][key], +8 pad
  __shared__ __align__(16) _Float16 Ps[4][16 * 72];   // per-wave P, [row][key]
  const int bh = blockIdx.y;
  const int r0 = blockIdx.x * 64;
  const int tid = threadIdx.x, lane = tid & 63, wave = tid >> 6;
  const int mcol = lane & 15, quad = lane >> 4;

  float aq_ = amax[bh], ak_ = amax[32 + bh];
  float sq = 448.f / fmaxf(aq_, 1e-12f), sk = 448.f / fmaxf(ak_, 1e-12f);
  const float factor = (1.f / (sq * sk)) * 0.125f;   // dequant * D^-0.5

  const size_t pbase = (size_t)bh * NDH;
  const int qrow = r0 + wave * 16 + mcol;
  long aq0 = *(const long*)(q8 + pbase + (size_t)qrow * 64 + quad * 8);
  long aq1 = *(const long*)(q8 + pbase + (size_t)qrow * 64 + 32 + quad * 8);

  f32x4 O[4] = {};
  float m_i[4], l_i[4];
#pragma unroll
  for (int r = 0; r < 4; ++r) { m_i[r] = -INFINITY; l_i[r] = 0.f; }

  const int ntiles = blockIdx.x + 1;
  for (int t = 0; t < ntiles; ++t) {
    const int n0 = t * 64;
    {
      int key = tid >> 2, dc = tid & 3;
      *(int4*)&K8s[key * 80 + dc * 16] =
          *(const int4*)(k8 + pbase + (size_t)(n0 + key) * 64 + dc * 16);
#pragma unroll
      for (int r = 0; r < 2; ++r) {
        int idx = tid + r * 256;
        int d = idx >> 3, ch = idx & 7;
        *(int4*)&Vt[d * 72 + ch * 8] =
            *(const int4*)(vh + ((size_t)bh * 64 + d) * 2048 + n0 + ch * 8);
      }
    }
    __syncthreads();

    // S = Q K^T (fp8 MFMA), C-layout: col=lane&15, row=quad*4+reg
    f32x4 s[4];
#pragma unroll
    for (int ct = 0; ct < 4; ++ct) {
      long bk0 = *(const long*)&K8s[(ct * 16 + mcol) * 80 + quad * 8];
      long bk1 = *(const long*)&K8s[(ct * 16 + mcol) * 80 + 32 + quad * 8];
      f32x4 z = {};
      z = __builtin_amdgcn_mfma_f32_16x16x32_fp8_fp8(aq0, bk0, z, 0, 0, 0);
      z = __builtin_amdgcn_mfma_f32_16x16x32_fp8_fp8(aq1, bk1, z, 0, 0, 0);
      s[ct] = z;
    }

    // online softmax
    float p[4][4], alpha[4];
#pragma unroll
    for (int reg = 0; reg < 4; ++reg) {
      int r = r0 + wave * 16 + quad * 4 + reg;
      float mx = -INFINITY;
#pragma unroll
      for (int ct = 0; ct < 4; ++ct) {
        int c = n0 + ct * 16 + mcol;
        float v = s[ct][reg] * factor;
        v = (c <= r) ? v : -INFINITY;
        p[ct][reg] = v;
        mx = fmaxf(mx, v);
      }
      mx = fmaxf(mx, __shfl_xor(mx, 1, 16));
      mx = fmaxf(mx, __shfl_xor(mx, 2, 16));
      mx = fmaxf(mx, __shfl_xor(mx, 4, 16));
      mx = fmaxf(mx, __shfl_xor(mx, 8, 16));
      float mn = fmaxf(m_i[reg], mx);
      alpha[reg] = (mn == -INFINITY) ? 1.f : __expf(m_i[reg] - mn);
      float su = 0.f;
#pragma unroll
      for (int ct = 0; ct < 4; ++ct) {
        float pv = (p[ct][reg] == -INFINITY) ? 0.f : __expf(p[ct][reg] - mn);
        p[ct][reg] = pv;
        su += pv;
      }
      su += __shfl_xor(su, 1, 16);
      su += __shfl_xor(su, 2, 16);
      su += __shfl_xor(su, 4, 16);
      su += __shfl_xor(su, 8, 16);
      l_i[reg] = l_i[reg] * alpha[reg] + su;
      m_i[reg] = mn;
    }
#pragma unroll
    for (int dt = 0; dt < 4; ++dt)
#pragma unroll
      for (int reg = 0; reg < 4; ++reg)
        O[dt][reg] *= alpha[reg];

    // P -> LDS (C-layout -> A-layout roundtrip)
    _Float16* Pw = &Ps[wave][0];
#pragma unroll
    for (int ct = 0; ct < 4; ++ct)
#pragma unroll
      for (int reg = 0; reg < 4; ++reg)
        Pw[(quad * 4 + reg) * 72 + ct * 16 + mcol] = (_Float16)p[ct][reg];
    __syncthreads();

    // O += P V (f16 MFMA)
#pragma unroll
    for (int kb = 0; kb < 2; ++kb) {
      f16x8 pa = *(const f16x8*)&Pw[mcol * 72 + kb * 32 + quad * 8];
#pragma unroll
      for (int dt = 0; dt < 4; ++dt) {
        f16x8 vb = *(const f16x8*)&Vt[(dt * 16 + mcol) * 72 + kb * 32 + quad * 8];
        O[dt] = __builtin_amdgcn_mfma_f32_16x16x32_f16(pa, vb, O[dt], 0, 0, 0);
      }
    }
    __syncthreads();
  }

  // epilogue -> attn [B,N,C] fp16
  int b = bh >> 4, h = bh & 15;
#pragma unroll
  for (int dt = 0; dt < 4; ++dt)
#pragma unroll
    for (int reg = 0; reg < 4; ++reg) {
      int r = r0 + wave * 16 + quad * 4 + reg;
      int d = dt * 16 + mcol;
      float val = O[dt][reg] / l_i[reg];
      attn[((size_t)b * 2048 + r) * 1024 + h * 64 + d] = (_Float16)val;
    }
}

// ---------------- GEMM2: out = attn @ w_proj + b ----------------
__global__ __launch_bounds__(256) void k_gemm_out(const _Float16* __restrict__ A,
                                                  const _Float16* __restrict__ BT,
                                                  const float* __restrict__ bias,
                                                  float* __restrict__ out) {
  __shared__ __align__(16) _Float16 As[128 * 40];
  __shared__ __align__(16) _Float16 Bs[128 * 40];
  const int tid = threadIdx.x, lane = tid & 63, wave = tid >> 6;
  const int wm = wave >> 1, wn = wave & 1;
  const int mcol = lane & 15, quad = lane >> 4;
  const int m0 = blockIdx.x * 128, n0 = blockIdx.y * 128;
  f32x4 acc[4][4] = {};
  for (int k0 = 0; k0 < 1024; k0 += 32) {
#pragma unroll
    for (int r = 0; r < 2; ++r) {
      int chunk = tid + r * 256;
      int row = chunk >> 2, kc = chunk & 3;
      *(int4*)&As[row * 40 + kc * 8] = *(const int4*)(A  + (size_t)(m0 + row) * 1024 + k0 + kc * 8);
      *(int4*)&Bs[row * 40 + kc * 8] = *(const int4*)(BT + (size_t)(n0 + row) * 1024 + k0 + kc * 8);
    }
    __syncthreads();
    f16x8 af[4], bf[4];
#pragma unroll
    for (int tm = 0; tm < 4; ++tm)
      af[tm] = *(const f16x8*)&As[(wm * 64 + tm * 16 + mcol) * 40 + quad * 8];
#pragma unroll
    for (int tn = 0; tn < 4; ++tn)
      bf[tn] = *(const f16x8*)&Bs[(wn * 64 + tn * 16 + mcol) * 40 + quad * 8];
#pragma unroll
    for (int tm = 0; tm < 4; ++tm)
#pragma unroll
      for (int tn = 0; tn < 4; ++tn)
        acc[tm][tn] = __builtin_amdgcn_mfma_f32_16x16x32_f16(af[tm], bf[tn], acc[tm][tn], 0, 0, 0);
    __syncthreads();
  }
#pragma unroll
  for (int tm = 0; tm < 4; ++tm)
#pragma unroll
    for (int tn = 0; tn < 4; ++tn)
#pragma unroll
      for (int reg = 0; reg < 4; ++reg) {
        int row = m0 + wm * 64 + tm * 16 + quad * 4 + reg;
        int col = n0 + wn * 64 + tn * 16 + mcol;
        out[(size_t)row * 1024 + col] = acc[tm][tn][reg] + bias[col];
      }
}

extern "C" void kernel_launch(void* const* d_in, const int* in_sizes, int n_in,
                              void* d_out, int out_size, void* d_ws, size_t ws_size,
                              hipStream_t stream) {
  const float* x      = (const float*)d_in[0];
  const float* w_qkv  = (const float*)d_in[1];
  const float* w_proj = (const float*)d_in[2];
  const float* b_proj = (const float*)d_in[3];
  float* out = (float*)d_out;

  char* ws = (char*)d_ws;
  _Float16* xh   = (_Float16*)ws; ws += (size_t)M1 * C_ * 2;          // 8 MB
  _Float16* whT  = (_Float16*)ws; ws += (size_t)3 * C_ * C_ * 2;      // 6 MB
  _Float16* wpT  = (_Float16*)ws; ws += (size_t)C_ * C_ * 2;          // 2 MB
  float*    qf   = (float*)ws;    ws += (size_t)BH_ * NDH * 4;        // 16 MB
  float*    kf   = (float*)ws;    ws += (size_t)BH_ * NDH * 4;        // 16 MB
  _Float16* vh   = (_Float16*)ws; ws += (size_t)BH_ * NDH * 2;        // 8 MB
  char*     q8   = (char*)ws;     ws += (size_t)BH_ * NDH;            // 4 MB
  char*     k8   = (char*)ws;     ws += (size_t)BH_ * NDH;            // 4 MB
  _Float16* attn = (_Float16*)ws; ws += (size_t)M1 * C_ * 2;          // 8 MB
  float*    amx  = (float*)ws;    ws += 256;

  // 1) dtype conversions / transposes
  k_cvt16<<<(M1 * C_ / 4 + 255) / 256, 256, 0, stream>>>(x, xh, M1 * C_ / 4);
  k_transpose16<<<dim3(3 * C_ / 64, C_ / 64), 256, 0, stream>>>(w_qkv, whT, C_, 3 * C_);
  k_transpose16<<<dim3(C_ / 64, C_ / 64), 256, 0, stream>>>(w_proj, wpT, C_, C_);
  // 2) qkv GEMM with q/k/v scatter
  k_gemm_qkv<<<dim3(M1 / 128, 3 * C_ / 128), 256, 0, stream>>>(xh, whT, qf, kf, vh);
  // 3) per-(b,h) amax, 4) fp8 quantize
  k_amax<<<64, 256, 0, stream>>>(qf, kf, amx);
  k_quant<<<4096, 256, 0, stream>>>(qf, kf, amx, q8, k8);
  // 5) flash causal attention
  k_flash<<<dim3(N_ / 64, BH_), 256, 0, stream>>>(q8, k8, vh, amx, attn);
  // 6) output projection
  k_gemm_out<<<dim3(M1 / 128, C_ / 128), 256, 0, stream>>>(attn, wpT, b_proj, out);
}

// Round 2
// 283.606 us; speedup vs baseline: 1.0908x; 1.0908x over previous
//
#include <hip/hip_runtime.h>

// Problem constants
#define B_   2
#define N_   2048
#define C_   1024
#define H_   16
#define D_   64
#define BH_  (B_*H_)      // 32
#define NDH  (N_*D_)      // 131072 elems per (b,h) plane
#define M1   (B_*N_)      // 4096 rows

typedef __attribute__((ext_vector_type(4))) float    f32x4;
typedef __attribute__((ext_vector_type(8))) _Float16 f16x8;
typedef __attribute__((ext_vector_type(4))) _Float16 f16x4;

// ---------------- fp32 -> fp16 convert ----------------
__global__ void k_cvt16(const float* __restrict__ in, _Float16* __restrict__ out, int n4) {
  int i = blockIdx.x * blockDim.x + threadIdx.x;
  if (i >= n4) return;
  float4 v = ((const float4*)in)[i];
  f16x4 o;
  o.x = (_Float16)v.x; o.y = (_Float16)v.y; o.z = (_Float16)v.z; o.w = (_Float16)v.w;
  ((f16x4*)out)[i] = o;
}

// ------------- fp32 [R][Cc] -> fp16 [Cc][R] transpose-convert -------------
__global__ __launch_bounds__(256) void k_transpose16(const float* __restrict__ in,
                                                     _Float16* __restrict__ out,
                                                     int R, int Cc) {
  __shared__ _Float16 t[64][68];   // +4 pad breaks bank conflicts
  int c0 = blockIdx.x * 64, r0 = blockIdx.y * 64;
  int tid = threadIdx.x;
  int cq = tid & 15, rq = tid >> 4;
#pragma unroll
  for (int i = 0; i < 4; ++i) {
    int r = rq + i * 16;
    float4 v = *(const float4*)(in + (size_t)(r0 + r) * Cc + c0 + cq * 4);
    t[r][cq*4+0] = (_Float16)v.x;
    t[r][cq*4+1] = (_Float16)v.y;
    t[r][cq*4+2] = (_Float16)v.z;
    t[r][cq*4+3] = (_Float16)v.w;
  }
  __syncthreads();
#pragma unroll
  for (int i = 0; i < 4; ++i) {
    int c = rq + i * 16;
    f16x4 o;
    o.x = t[cq*4+0][c];
    o.y = t[cq*4+1][c];
    o.z = t[cq*4+2][c];
    o.w = t[cq*4+3][c];
    *(f16x4*)(out + (size_t)(c0 + c) * R + r0 + cq * 4) = o;
  }
}

// ---------------- GEMM1: qkv = x @ w_qkv, scatter epilogue ----------------
__global__ __launch_bounds__(256) void k_gemm_qkv(const _Float16* __restrict__ A,
                                                  const _Float16* __restrict__ BT,
                                                  float* __restrict__ qf,
                                                  float* __restrict__ kf,
                                                  _Float16* __restrict__ vh) {
  __shared__ __align__(16) _Float16 As[128 * 40];
  __shared__ __align__(16) _Float16 Bs[128 * 40];
  const int tid = threadIdx.x, lane = tid & 63, wave = tid >> 6;
  const int wm = wave >> 1, wn = wave & 1;
  const int mcol = lane & 15, quad = lane >> 4;
  const int m0 = blockIdx.x * 128, n0 = blockIdx.y * 128;
  f32x4 acc[4][4] = {};
  for (int k0 = 0; k0 < 1024; k0 += 32) {
#pragma unroll
    for (int r = 0; r < 2; ++r) {
      int chunk = tid + r * 256;
      int row = chunk >> 2, kc = chunk & 3;
      *(int4*)&As[row * 40 + kc * 8] = *(const int4*)(A  + (size_t)(m0 + row) * 1024 + k0 + kc * 8);
      *(int4*)&Bs[row * 40 + kc * 8] = *(const int4*)(BT + (size_t)(n0 + row) * 1024 + k0 + kc * 8);
    }
    __syncthreads();
    f16x8 af[4], bf[4];
#pragma unroll
    for (int tm = 0; tm < 4; ++tm)
      af[tm] = *(const f16x8*)&As[(wm * 64 + tm * 16 + mcol) * 40 + quad * 8];
#pragma unroll
    for (int tn = 0; tn < 4; ++tn)
      bf[tn] = *(const f16x8*)&Bs[(wn * 64 + tn * 16 + mcol) * 40 + quad * 8];
#pragma unroll
    for (int tm = 0; tm < 4; ++tm)
#pragma unroll
      for (int tn = 0; tn < 4; ++tn)
        acc[tm][tn] = __builtin_amdgcn_mfma_f32_16x16x32_f16(af[tm], bf[tn], acc[tm][tn], 0, 0, 0);
    __syncthreads();
  }
  const int sec = n0 >> 10;
  if (sec < 2) {
    float* dst = sec ? kf : qf;
#pragma unroll
    for (int tm = 0; tm < 4; ++tm)
#pragma unroll
      for (int tn = 0; tn < 4; ++tn)
#pragma unroll
        for (int reg = 0; reg < 4; ++reg) {
          int row = m0 + wm * 64 + tm * 16 + quad * 4 + reg;
          int col = n0 + wn * 64 + tn * 16 + mcol;
          int cc = col & 1023, h = cc >> 6, d = cc & 63;
          int b = row >> 11, n = row & 2047;
          dst[((size_t)(b * 16 + h) * 2048 + n) * 64 + d] = acc[tm][tn][reg];
        }
  } else {
#pragma unroll
    for (int tm = 0; tm < 4; ++tm)
#pragma unroll
      for (int tn = 0; tn < 4; ++tn) {
        int rowb = m0 + wm * 64 + tm * 16 + quad * 4;
        int col = n0 + wn * 64 + tn * 16 + mcol;
        int cc = col & 1023, h = cc >> 6, d = cc & 63;
        int b = rowb >> 11, n = rowb & 2047;
        f16x4 o;
        o.x = (_Float16)acc[tm][tn][0];
        o.y = (_Float16)acc[tm][tn][1];
        o.z = (_Float16)acc[tm][tn][2];
        o.w = (_Float16)acc[tm][tn][3];
        *(f16x4*)&vh[((size_t)(b * 16 + h) * 64 + d) * 2048 + n] = o;
      }
  }
}

// ---------------- per-(b,h) amax of q and k ----------------
__global__ __launch_bounds__(256) void k_amax(const float* __restrict__ qf,
                                              const float* __restrict__ kf,
                                              float* __restrict__ amax) {
  int b = blockIdx.x;
  const float* src = (b < 32 ? qf : kf) + (size_t)(b & 31) * NDH;
  int tid = threadIdx.x;
  float mx = 0.f;
  for (int i = tid; i < NDH / 4; i += 256) {
    float4 v = ((const float4*)src)[i];
    mx = fmaxf(mx, fmaxf(fmaxf(fabsf(v.x), fabsf(v.y)), fmaxf(fabsf(v.z), fabsf(v.w))));
  }
#pragma unroll
  for (int off = 32; off; off >>= 1) mx = fmaxf(mx, __shfl_xor(mx, off, 64));
  __shared__ float red[4];
  if ((tid & 63) == 0) red[tid >> 6] = mx;
  __syncthreads();
  if (tid == 0) amax[b] = fmaxf(fmaxf(red[0], red[1]), fmaxf(red[2], red[3]));
}

// ---------------- fp8 e4m3 quantize ----------------
__global__ __launch_bounds__(256) void k_quant(const float* __restrict__ qf,
                                               const float* __restrict__ kf,
                                               const float* __restrict__ amax,
                                               char* __restrict__ q8,
                                               char* __restrict__ k8) {
  int blk = blockIdx.x;
  int which = blk >> 11;
  int idx = blk & 2047;
  int bh = idx >> 6, chunk = idx & 63;
  const float* src = (which ? kf : qf) + (size_t)bh * NDH + chunk * 2048;
  char* dst = (which ? k8 : q8) + (size_t)bh * NDH + chunk * 2048;
  float s = 448.f / fmaxf(amax[which * 32 + bh], 1e-12f);
  int t = threadIdx.x;
  float4 a = ((const float4*)(src + t * 8))[0];
  float4 c = ((const float4*)(src + t * 8))[1];
  int lo = 0, hi = 0;
  lo = __builtin_amdgcn_cvt_pk_fp8_f32(a.x * s, a.y * s, lo, false);
  lo = __builtin_amdgcn_cvt_pk_fp8_f32(a.z * s, a.w * s, lo, true);
  hi = __builtin_amdgcn_cvt_pk_fp8_f32(c.x * s, c.y * s, hi, false);
  hi = __builtin_amdgcn_cvt_pk_fp8_f32(c.z * s, c.w * s, hi, true);
  int2 o; o.x = lo; o.y = hi;
  *(int2*)(dst + t * 8) = o;
}

// ---------------- flash causal attention (1 wave / block, no barriers) ----
// grid (32 bh, 128 row-groups of 16). S^T = K·Q^T via fp8 MFMA so each lane
// owns one q-row: row max/sum = in-lane + 2 shuffles; m/l are lane scalars.
// K/V frags straight from global (L2-hot), P roundtrip in per-wave LDS.
__global__ __launch_bounds__(64, 4) void k_flash(const char* __restrict__ q8,
                                                 const char* __restrict__ k8,
                                                 const _Float16* __restrict__ vh,
                                                 const float* __restrict__ amax,
                                                 _Float16* __restrict__ attn) {
  __shared__ __align__(16) _Float16 P[16][72];
  const int bh = blockIdx.x;          // bh%8 pins K/V plane to one XCD's L2
  const int xg = blockIdx.y;          // 16-row q group
  const int lane = threadIdx.x;
  const int mcol = lane & 15, quad = lane >> 4;
  const int qrow = xg * 16 + mcol;

  float sq = 448.f / fmaxf(amax[bh], 1e-12f);
  float sk = 448.f / fmaxf(amax[32 + bh], 1e-12f);
  const float c2 = (1.f / (sq * sk)) * 0.125f * 1.44269504089f;  // dequant*scale*log2e

  const size_t pbase = (size_t)bh * NDH;
  const char* qp = q8 + pbase + (size_t)qrow * 64;
  long aq0 = *(const long*)(qp + quad * 8);
  long aq1 = *(const long*)(qp + 32 + quad * 8);

  f32x4 O[4] = {};
  float m_i = -3e38f, l_i = 0.f;
  const int tlast = xg >> 2;
  const _Float16* vbase = vh + (size_t)bh * 64 * 2048;

  for (int t = 0; t <= tlast; ++t) {
    const int n0 = t * 64;
    // K fragments (A-operand): lane holds key=ct*16+mcol, bytes quad*8..
    long bk[4][2];
    const char* kp = k8 + pbase + (size_t)n0 * 64;
#pragma unroll
    for (int ct = 0; ct < 4; ++ct) {
      bk[ct][0] = *(const long*)(kp + (size_t)(ct * 16 + mcol) * 64 + quad * 8);
      bk[ct][1] = *(const long*)(kp + (size_t)(ct * 16 + mcol) * 64 + 32 + quad * 8);
    }
    // V^T fragments (A-operand for PV): lane holds d=dt*16+mcol, keys quad*8..
    f16x8 vf[4][2];
#pragma unroll
    for (int dt = 0; dt < 4; ++dt) {
      const _Float16* vp = vbase + (size_t)(dt * 16 + mcol) * 2048 + n0;
      vf[dt][0] = *(const f16x8*)(vp + quad * 8);
      vf[dt][1] = *(const f16x8*)(vp + 32 + quad * 8);
    }
    // S^T = K·Q^T : D[m=key][n=qrow], lane owns qrow = xg*16+mcol
    f32x4 s[4];
#pragma unroll
    for (int ct = 0; ct < 4; ++ct) {
      f32x4 z = {};
      z = __builtin_amdgcn_mfma_f32_16x16x32_fp8_fp8(bk[ct][0], aq0, z, 0, 0, 0);
      z = __builtin_amdgcn_mfma_f32_16x16x32_fp8_fp8(bk[ct][1], aq1, z, 0, 0, 0);
      s[ct] = z;
    }
    // scale (base-2) + causal mask (diagonal tile only) + running row max
    float mx = m_i;
    if (t == tlast) {
#pragma unroll
      for (int ct = 0; ct < 4; ++ct)
#pragma unroll
        for (int r = 0; r < 4; ++r) {
          int key = n0 + ct * 16 + quad * 4 + r;
          float v = s[ct][r] * c2;
          v = (key <= qrow) ? v : -3e38f;
          s[ct][r] = v;
          mx = fmaxf(mx, v);
        }
    } else {
#pragma unroll
      for (int ct = 0; ct < 4; ++ct)
#pragma unroll
        for (int r = 0; r < 4; ++r) {
          float v = s[ct][r] * c2;
          s[ct][r] = v;
          mx = fmaxf(mx, v);
        }
    }
    mx = fmaxf(mx, __shfl_xor(mx, 16));
    mx = fmaxf(mx, __shfl_xor(mx, 32));
    float alpha = exp2f(m_i - mx);
    m_i = mx;
    float sum = 0.f;
#pragma unroll
    for (int ct = 0; ct < 4; ++ct) {
#pragma unroll
      for (int r = 0; r < 4; ++r) {
        float p = exp2f(s[ct][r] - mx);
        s[ct][r] = p;
        sum += p;
      }
      // P[qrow][key]: 4 consecutive keys -> one 8B LDS write
      f16x4 w;
      w.x = (_Float16)s[ct][0];
      w.y = (_Float16)s[ct][1];
      w.z = (_Float16)s[ct][2];
      w.w = (_Float16)s[ct][3];
      *(f16x4*)&P[mcol][ct * 16 + quad * 4] = w;
    }
    sum += __shfl_xor(sum, 16);
    sum += __shfl_xor(sum, 32);
    l_i = l_i * alpha + sum;
#pragma unroll
    for (int dt = 0; dt < 4; ++dt)
#pragma unroll
      for (int r = 0; r < 4; ++r)
        O[dt][r] *= alpha;
    // O^T += V^T · P  (B-operand P from per-wave LDS; in-order DS, no barrier)
#pragma unroll
    for (int kb = 0; kb < 2; ++kb) {
      f16x8 pb = *(const f16x8*)&P[mcol][kb * 32 + quad * 8];
#pragma unroll
      for (int dt = 0; dt < 4; ++dt)
        O[dt] = __builtin_amdgcn_mfma_f32_16x16x32_f16(vf[dt][kb], pb, O[dt], 0, 0, 0);
    }
  }

  // epilogue: lane holds qrow = xg*16+mcol, d = dt*16+quad*4+reg
  float rl = 1.f / l_i;
  int b = bh >> 4, h = bh & 15;
  _Float16* op = attn + ((size_t)b * 2048 + qrow) * 1024 + h * 64;
#pragma unroll
  for (int dt = 0; dt < 4; ++dt) {
    f16x4 o;
    o.x = (_Float16)(O[dt][0] * rl);
    o.y = (_Float16)(O[dt][1] * rl);
    o.z = (_Float16)(O[dt][2] * rl);
    o.w = (_Float16)(O[dt][3] * rl);
    *(f16x4*)(op + dt * 16 + quad * 4) = o;
  }
}

// ---------------- GEMM2: out = attn @ w_proj + b ----------------
__global__ __launch_bounds__(256) void k_gemm_out(const _Float16* __restrict__ A,
                                                  const _Float16* __restrict__ BT,
                                                  const float* __restrict__ bias,
                                                  float* __restrict__ out) {
  __shared__ __align__(16) _Float16 As[128 * 40];
  __shared__ __align__(16) _Float16 Bs[128 * 40];
  const int tid = threadIdx.x, lane = tid & 63, wave = tid >> 6;
  const int wm = wave >> 1, wn = wave & 1;
  const int mcol = lane & 15, quad = lane >> 4;
  const int m0 = blockIdx.x * 128, n0 = blockIdx.y * 128;
  f32x4 acc[4][4] = {};
  for (int k0 = 0; k0 < 1024; k0 += 32) {
#pragma unroll
    for (int r = 0; r < 2; ++r) {
      int chunk = tid + r * 256;
      int row = chunk >> 2, kc = chunk & 3;
      *(int4*)&As[row * 40 + kc * 8] = *(const int4*)(A  + (size_t)(m0 + row) * 1024 + k0 + kc * 8);
      *(int4*)&Bs[row * 40 + kc * 8] = *(const int4*)(BT + (size_t)(n0 + row) * 1024 + k0 + kc * 8);
    }
    __syncthreads();
    f16x8 af[4], bf[4];
#pragma unroll
    for (int tm = 0; tm < 4; ++tm)
      af[tm] = *(const f16x8*)&As[(wm * 64 + tm * 16 + mcol) * 40 + quad * 8];
#pragma unroll
    for (int tn = 0; tn < 4; ++tn)
      bf[tn] = *(const f16x8*)&Bs[(wn * 64 + tn * 16 + mcol) * 40 + quad * 8];
#pragma unroll
    for (int tm = 0; tm < 4; ++tm)
#pragma unroll
      for (int tn = 0; tn < 4; ++tn)
        acc[tm][tn] = __builtin_amdgcn_mfma_f32_16x16x32_f16(af[tm], bf[tn], acc[tm][tn], 0, 0, 0);
    __syncthreads();
  }
#pragma unroll
  for (int tm = 0; tm < 4; ++tm)
#pragma unroll
    for (int tn = 0; tn < 4; ++tn)
#pragma unroll
      for (int reg = 0; reg < 4; ++reg) {
        int row = m0 + wm * 64 + tm * 16 + quad * 4 + reg;
        int col = n0 + wn * 64 + tn * 16 + mcol;
        out[(size_t)row * 1024 + col] = acc[tm][tn][reg] + bias[col];
      }
}

extern "C" void kernel_launch(void* const* d_in, const int* in_sizes, int n_in,
                              void* d_out, int out_size, void* d_ws, size_t ws_size,
                              hipStream_t stream) {
  const float* x      = (const float*)d_in[0];
  const float* w_qkv  = (const float*)d_in[1];
  const float* w_proj = (const float*)d_in[2];
  const float* b_proj = (const float*)d_in[3];
  float* out = (float*)d_out;

  char* ws = (char*)d_ws;
  _Float16* xh   = (_Float16*)ws; ws += (size_t)M1 * C_ * 2;
  _Float16* whT  = (_Float16*)ws; ws += (size_t)3 * C_ * C_ * 2;
  _Float16* wpT  = (_Float16*)ws; ws += (size_t)C_ * C_ * 2;
  float*    qf   = (float*)ws;    ws += (size_t)BH_ * NDH * 4;
  float*    kf   = (float*)ws;    ws += (size_t)BH_ * NDH * 4;
  _Float16* vh   = (_Float16*)ws; ws += (size_t)BH_ * NDH * 2;
  char*     q8   = (char*)ws;     ws += (size_t)BH_ * NDH;
  char*     k8   = (char*)ws;     ws += (size_t)BH_ * NDH;
  _Float16* attn = (_Float16*)ws; ws += (size_t)M1 * C_ * 2;
  float*    amx  = (float*)ws;    ws += 256;

  k_cvt16<<<(M1 * C_ / 4 + 255) / 256, 256, 0, stream>>>(x, xh, M1 * C_ / 4);
  k_transpose16<<<dim3(3 * C_ / 64, C_ / 64), 256, 0, stream>>>(w_qkv, whT, C_, 3 * C_);
  k_transpose16<<<dim3(C_ / 64, C_ / 64), 256, 0, stream>>>(w_proj, wpT, C_, C_);
  k_gemm_qkv<<<dim3(M1 / 128, 3 * C_ / 128), 256, 0, stream>>>(xh, whT, qf, kf, vh);
  k_amax<<<64, 256, 0, stream>>>(qf, kf, amx);
  k_quant<<<4096, 256, 0, stream>>>(qf, kf, amx, q8, k8);
  k_flash<<<dim3(32, 128), 64, 0, stream>>>(q8, k8, vh, amx, attn);
  k_gemm_out<<<dim3(M1 / 128, C_ / 128), 256, 0, stream>>>(attn, wpT, b_proj, out);
}

// Round 3
// 263.616 us; speedup vs baseline: 1.1735x; 1.0758x over previous
//
#include <hip/hip_runtime.h>

// Problem constants
#define B_   2
#define N_   2048
#define C_   1024
#define H_   16
#define D_   64
#define BH_  (B_*H_)      // 32
#define NDH  (N_*D_)      // 131072 elems per (b,h) plane
#define M1   (B_*N_)      // 4096 rows

typedef __attribute__((ext_vector_type(4))) float    f32x4;
typedef __attribute__((ext_vector_type(8))) _Float16 f16x8;
typedef __attribute__((ext_vector_type(4))) _Float16 f16x4;

// ---------------- fp32 -> fp16 convert ----------------
__global__ void k_cvt16(const float* __restrict__ in, _Float16* __restrict__ out, int n4) {
  int i = blockIdx.x * blockDim.x + threadIdx.x;
  if (i >= n4) return;
  float4 v = ((const float4*)in)[i];
  f16x4 o;
  o.x = (_Float16)v.x; o.y = (_Float16)v.y; o.z = (_Float16)v.z; o.w = (_Float16)v.w;
  ((f16x4*)out)[i] = o;
}

// --- merged fp32->fp16 transpose for w_qkv and w_proj (+ amax zero-init) ---
__global__ __launch_bounds__(256) void k_transmerge(const float* __restrict__ wq,
                                                    const float* __restrict__ wp,
                                                    _Float16* __restrict__ whT,
                                                    _Float16* __restrict__ wpT,
                                                    unsigned* __restrict__ amax_u) {
  if (blockIdx.x == 0 && threadIdx.x < 64) amax_u[threadIdx.x] = 0u;  // runs before gemm_qkv (stream order)
  __shared__ _Float16 t[64][68];
  int idx = blockIdx.x;
  const float* in; _Float16* out; int Cc, cx, cy;
  if (idx < 768) { in = wq; out = whT; Cc = 3072; cx = idx % 48; cy = idx / 48; }
  else { idx -= 768; in = wp; out = wpT; Cc = 1024; cx = idx % 16; cy = idx / 16; }
  const int R = 1024;
  int c0 = cx * 64, r0 = cy * 64;
  int tid = threadIdx.x;
  int cq = tid & 15, rq = tid >> 4;
#pragma unroll
  for (int i = 0; i < 4; ++i) {
    int r = rq + i * 16;
    float4 v = *(const float4*)(in + (size_t)(r0 + r) * Cc + c0 + cq * 4);
    t[r][cq*4+0] = (_Float16)v.x;
    t[r][cq*4+1] = (_Float16)v.y;
    t[r][cq*4+2] = (_Float16)v.z;
    t[r][cq*4+3] = (_Float16)v.w;
  }
  __syncthreads();
#pragma unroll
  for (int i = 0; i < 4; ++i) {
    int c = rq + i * 16;
    f16x4 o;
    o.x = t[cq*4+0][c];
    o.y = t[cq*4+1][c];
    o.z = t[cq*4+2][c];
    o.w = t[cq*4+3][c];
    *(f16x4*)(out + (size_t)(c0 + c) * R + r0 + cq * 4) = o;
  }
}

// ---------------- GEMM1: qkv = x @ w_qkv, scatter epilogue + fused amax ---
__global__ __launch_bounds__(256) void k_gemm_qkv(const _Float16* __restrict__ A,
                                                  const _Float16* __restrict__ BT,
                                                  float* __restrict__ qf,
                                                  float* __restrict__ kf,
                                                  _Float16* __restrict__ vh,
                                                  unsigned* __restrict__ amax_u) {
  __shared__ __align__(16) _Float16 As[128 * 40];
  __shared__ __align__(16) _Float16 Bs[128 * 40];
  const int tid = threadIdx.x, lane = tid & 63, wave = tid >> 6;
  const int wm = wave >> 1, wn = wave & 1;
  const int mcol = lane & 15, quad = lane >> 4;
  const int m0 = blockIdx.x * 128, n0 = blockIdx.y * 128;
  f32x4 acc[4][4] = {};
  for (int k0 = 0; k0 < 1024; k0 += 32) {
#pragma unroll
    for (int r = 0; r < 2; ++r) {
      int chunk = tid + r * 256;
      int row = chunk >> 2, kc = chunk & 3;
      *(int4*)&As[row * 40 + kc * 8] = *(const int4*)(A  + (size_t)(m0 + row) * 1024 + k0 + kc * 8);
      *(int4*)&Bs[row * 40 + kc * 8] = *(const int4*)(BT + (size_t)(n0 + row) * 1024 + k0 + kc * 8);
    }
    __syncthreads();
    f16x8 af[4], bf[4];
#pragma unroll
    for (int tm = 0; tm < 4; ++tm)
      af[tm] = *(const f16x8*)&As[(wm * 64 + tm * 16 + mcol) * 40 + quad * 8];
#pragma unroll
    for (int tn = 0; tn < 4; ++tn)
      bf[tn] = *(const f16x8*)&Bs[(wn * 64 + tn * 16 + mcol) * 40 + quad * 8];
#pragma unroll
    for (int tm = 0; tm < 4; ++tm)
#pragma unroll
      for (int tn = 0; tn < 4; ++tn)
        acc[tm][tn] = __builtin_amdgcn_mfma_f32_16x16x32_f16(af[tm], bf[tn], acc[tm][tn], 0, 0, 0);
    __syncthreads();
  }
  const int sec = n0 >> 10;
  if (sec < 2) {
    float* dst = sec ? kf : qf;
    float mxv = 0.f;
#pragma unroll
    for (int tm = 0; tm < 4; ++tm)
#pragma unroll
      for (int tn = 0; tn < 4; ++tn)
#pragma unroll
        for (int reg = 0; reg < 4; ++reg) {
          int row = m0 + wm * 64 + tm * 16 + quad * 4 + reg;
          int col = n0 + wn * 64 + tn * 16 + mcol;
          int cc = col & 1023, h = cc >> 6, d = cc & 63;
          int b = row >> 11, n = row & 2047;
          float v = acc[tm][tn][reg];
          mxv = fmaxf(mxv, fabsf(v));
          dst[((size_t)(b * 16 + h) * 2048 + n) * 64 + d] = v;
        }
    // wave's values all belong to head h0+wn of batch m0>>11
#pragma unroll
    for (int off = 32; off; off >>= 1) mxv = fmaxf(mxv, __shfl_xor(mxv, off));
    if (lane == 0) {
      int head = ((n0 & 1023) >> 6) + wn;
      int plane = (m0 >> 11) * 16 + head;
      atomicMax(&amax_u[sec * 32 + plane], __float_as_uint(mxv));
    }
  } else {
#pragma unroll
    for (int tm = 0; tm < 4; ++tm)
#pragma unroll
      for (int tn = 0; tn < 4; ++tn) {
        int rowb = m0 + wm * 64 + tm * 16 + quad * 4;
        int col = n0 + wn * 64 + tn * 16 + mcol;
        int cc = col & 1023, h = cc >> 6, d = cc & 63;
        int b = rowb >> 11, n = rowb & 2047;
        f16x4 o;
        o.x = (_Float16)acc[tm][tn][0];
        o.y = (_Float16)acc[tm][tn][1];
        o.z = (_Float16)acc[tm][tn][2];
        o.w = (_Float16)acc[tm][tn][3];
        *(f16x4*)&vh[((size_t)(b * 16 + h) * 64 + d) * 2048 + n] = o;
      }
  }
}

// ---------------- fp8 e4m3 quantize ----------------
__global__ __launch_bounds__(256) void k_quant(const float* __restrict__ qf,
                                               const float* __restrict__ kf,
                                               const float* __restrict__ amax,
                                               char* __restrict__ q8,
                                               char* __restrict__ k8) {
  int blk = blockIdx.x;
  int which = blk >> 11;
  int idx = blk & 2047;
  int bh = idx >> 6, chunk = idx & 63;
  const float* src = (which ? kf : qf) + (size_t)bh * NDH + chunk * 2048;
  char* dst = (which ? k8 : q8) + (size_t)bh * NDH + chunk * 2048;
  float s = 448.f / fmaxf(amax[which * 32 + bh], 1e-12f);
  int t = threadIdx.x;
  float4 a = ((const float4*)(src + t * 8))[0];
  float4 c = ((const float4*)(src + t * 8))[1];
  int lo = 0, hi = 0;
  lo = __builtin_amdgcn_cvt_pk_fp8_f32(a.x * s, a.y * s, lo, false);
  lo = __builtin_amdgcn_cvt_pk_fp8_f32(a.z * s, a.w * s, lo, true);
  hi = __builtin_amdgcn_cvt_pk_fp8_f32(c.x * s, c.y * s, hi, false);
  hi = __builtin_amdgcn_cvt_pk_fp8_f32(c.z * s, c.w * s, hi, true);
  int2 o; o.x = lo; o.y = hi;
  *(int2*)(dst + t * 8) = o;
}

// ---------------- flash causal attention --------------------------------
// 4 independent waves/block, no barriers. Each wave handles the balanced
// pair of 16-row q-groups {g, 127-g}: exactly 17 128-key tiles per wave.
// S^T = K·Q^T (fp8 MFMA, lane owns one q-row); K register-prefetched one
// tile ahead (ping-pong); P roundtrip through per-wave LDS; PV f16 MFMA.
__global__ __launch_bounds__(256, 2) void k_flash(const char* __restrict__ q8,
                                                  const char* __restrict__ k8,
                                                  const _Float16* __restrict__ vh,
                                                  const float* __restrict__ amax,
                                                  _Float16* __restrict__ attn) {
  __shared__ __align__(16) _Float16 P[4][16][144];
  const int bh = blockIdx.x;          // bh%8 pins K/V plane to one XCD's L2
  const int wave = threadIdx.x >> 6, lane = threadIdx.x & 63;
  const int mcol = lane & 15, quad = lane >> 4;
  const int pr = blockIdx.y * 4 + wave;     // pair index 0..63
  const int ga = pr, gb = 127 - pr;
  const int ta = (ga >> 3) + 1;             // tiles for group a (1..8); total always 17

  float sq = 448.f / fmaxf(amax[bh], 1e-12f);
  float sk = 448.f / fmaxf(amax[32 + bh], 1e-12f);
  const float c2 = (1.f / (sq * sk)) * 0.125f * 1.44269504089f;  // dequant*scale*log2e

  const size_t pbase = (size_t)bh * NDH;
  const char* kbase = k8 + pbase;
  const _Float16* vbase = vh + (size_t)bh * 64 * 2048;
  const int qrowA = ga * 16 + mcol, qrowB = gb * 16 + mcol;
  long aqA0, aqA1, aqB0, aqB1;
  { const char* qp = q8 + pbase + (size_t)qrowA * 64;
    aqA0 = *(const long*)(qp + quad * 8); aqA1 = *(const long*)(qp + 32 + quad * 8); }
  { const char* qp = q8 + pbase + (size_t)qrowB * 64;
    aqB0 = *(const long*)(qp + quad * 8); aqB1 = *(const long*)(qp + 32 + quad * 8); }

  f32x4 O[4] = {};
  float m_i = -3e38f, l_i = 0.f;
  const int b = bh >> 4, h = bh & 15;

  long kc[8][2], kn[8][2];
#pragma unroll
  for (int ct = 0; ct < 8; ++ct) {          // tile 0 (group a, n0 = 0)
    const char* kp = kbase + (size_t)(ct * 16 + mcol) * 64;
    kc[ct][0] = *(const long*)(kp + quad * 8);
    kc[ct][1] = *(const long*)(kp + 32 + quad * 8);
  }

  auto body = [&](int t, long (&cur)[8][2], long (&nxt)[8][2]) {
    const bool inB = t >= ta;
    const int n0 = (inB ? t - ta : t) * 128;
    const long aq0 = inB ? aqB0 : aqA0;
    const long aq1 = inB ? aqB1 : aqA1;
    const int qrow = inB ? qrowB : qrowA;
    const bool last = inB ? (t == 16) : (t == ta - 1);

    // S^T = K·Q^T : lane owns q-row = qrow, regs hold 32 keys
    f32x4 s[8];
#pragma unroll
    for (int ct = 0; ct < 8; ++ct) {
      f32x4 z = {};
      z = __builtin_amdgcn_mfma_f32_16x16x32_fp8_fp8(cur[ct][0], aq0, z, 0, 0, 0);
      z = __builtin_amdgcn_mfma_f32_16x16x32_fp8_fp8(cur[ct][1], aq1, z, 0, 0, 0);
      s[ct] = z;
    }
    // prefetch K for tile t+1 (overlaps the softmax below)
    if (t < 16) {
      const int t2 = t + 1;
      const int n02 = ((t2 >= ta) ? t2 - ta : t2) * 128;
      const char* kp = kbase + (size_t)n02 * 64;
#pragma unroll
      for (int ct = 0; ct < 8; ++ct) {
        nxt[ct][0] = *(const long*)(kp + (size_t)(ct * 16 + mcol) * 64 + quad * 8);
        nxt[ct][1] = *(const long*)(kp + (size_t)(ct * 16 + mcol) * 64 + 32 + quad * 8);
      }
    }
    // V for first 64 keys (consumed after softmax)
    f16x8 vf[4][2];
#pragma unroll
    for (int dt = 0; dt < 4; ++dt) {
      const _Float16* vp = vbase + (size_t)(dt * 16 + mcol) * 2048 + n0;
      vf[dt][0] = *(const f16x8*)(vp + quad * 8);
      vf[dt][1] = *(const f16x8*)(vp + 32 + quad * 8);
    }
    // online softmax (base 2)
    float mx = m_i;
    if (last) {
#pragma unroll
      for (int ct = 0; ct < 8; ++ct)
#pragma unroll
        for (int r = 0; r < 4; ++r) {
          int key = n0 + ct * 16 + quad * 4 + r;
          float v = s[ct][r] * c2;
          v = (key <= qrow) ? v : -3e38f;
          s[ct][r] = v; mx = fmaxf(mx, v);
        }
    } else {
#pragma unroll
      for (int ct = 0; ct < 8; ++ct)
#pragma unroll
        for (int r = 0; r < 4; ++r) {
          float v = s[ct][r] * c2;
          s[ct][r] = v; mx = fmaxf(mx, v);
        }
    }
    mx = fmaxf(mx, __shfl_xor(mx, 16));
    mx = fmaxf(mx, __shfl_xor(mx, 32));
    float alpha = exp2f(m_i - mx);
    m_i = mx;
    float sum = 0.f;
#pragma unroll
    for (int ct = 0; ct < 8; ++ct) {
#pragma unroll
      for (int r = 0; r < 4; ++r) {
        float pv = exp2f(s[ct][r] - mx);
        s[ct][r] = pv; sum += pv;
      }
      f16x4 w;
      w.x = (_Float16)s[ct][0];
      w.y = (_Float16)s[ct][1];
      w.z = (_Float16)s[ct][2];
      w.w = (_Float16)s[ct][3];
      *(f16x4*)&P[wave][mcol][ct * 16 + quad * 4] = w;
    }
    sum += __shfl_xor(sum, 16);
    sum += __shfl_xor(sum, 32);
    l_i = l_i * alpha + sum;
#pragma unroll
    for (int dt = 0; dt < 4; ++dt)
#pragma unroll
      for (int r = 0; r < 4; ++r)
        O[dt][r] *= alpha;
    // PV keys 0..63
#pragma unroll
    for (int kb = 0; kb < 2; ++kb) {
      f16x8 pb = *(const f16x8*)&P[wave][mcol][kb * 32 + quad * 8];
#pragma unroll
      for (int dt = 0; dt < 4; ++dt)
        O[dt] = __builtin_amdgcn_mfma_f32_16x16x32_f16(vf[dt][kb], pb, O[dt], 0, 0, 0);
    }
    // V + PV keys 64..127
#pragma unroll
    for (int dt = 0; dt < 4; ++dt) {
      const _Float16* vp = vbase + (size_t)(dt * 16 + mcol) * 2048 + n0 + 64;
      vf[dt][0] = *(const f16x8*)(vp + quad * 8);
      vf[dt][1] = *(const f16x8*)(vp + 32 + quad * 8);
    }
#pragma unroll
    for (int kb = 0; kb < 2; ++kb) {
      f16x8 pb = *(const f16x8*)&P[wave][mcol][64 + kb * 32 + quad * 8];
#pragma unroll
      for (int dt = 0; dt < 4; ++dt)
        O[dt] = __builtin_amdgcn_mfma_f32_16x16x32_f16(vf[dt][kb], pb, O[dt], 0, 0, 0);
    }
    if (last) {  // emit this q-group, reset state for next group
      float rl = 1.f / l_i;
      _Float16* op = attn + ((size_t)b * 2048 + qrow) * 1024 + h * 64;
#pragma unroll
      for (int dt = 0; dt < 4; ++dt) {
        f16x4 o;
        o.x = (_Float16)(O[dt][0] * rl);
        o.y = (_Float16)(O[dt][1] * rl);
        o.z = (_Float16)(O[dt][2] * rl);
        o.w = (_Float16)(O[dt][3] * rl);
        *(f16x4*)(op + dt * 16 + quad * 4) = o;
        O[dt] = (f32x4){0.f, 0.f, 0.f, 0.f};
      }
      m_i = -3e38f; l_i = 0.f;
    }
  };

#pragma unroll 1
  for (int t = 0; t < 17; t += 2) {
    body(t, kc, kn);
    if (t + 1 < 17) body(t + 1, kn, kc);
  }
}

// ---------------- GEMM2: out = attn @ w_proj + b ----------------
__global__ __launch_bounds__(256) void k_gemm_out(const _Float16* __restrict__ A,
                                                  const _Float16* __restrict__ BT,
                                                  const float* __restrict__ bias,
                                                  float* __restrict__ out) {
  __shared__ __align__(16) _Float16 As[128 * 40];
  __shared__ __align__(16) _Float16 Bs[128 * 40];
  const int tid = threadIdx.x, lane = tid & 63, wave = tid >> 6;
  const int wm = wave >> 1, wn = wave & 1;
  const int mcol = lane & 15, quad = lane >> 4;
  const int m0 = blockIdx.x * 128, n0 = blockIdx.y * 128;
  f32x4 acc[4][4] = {};
  for (int k0 = 0; k0 < 1024; k0 += 32) {
#pragma unroll
    for (int r = 0; r < 2; ++r) {
      int chunk = tid + r * 256;
      int row = chunk >> 2, kc = chunk & 3;
      *(int4*)&As[row * 40 + kc * 8] = *(const int4*)(A  + (size_t)(m0 + row) * 1024 + k0 + kc * 8);
      *(int4*)&Bs[row * 40 + kc * 8] = *(const int4*)(BT + (size_t)(n0 + row) * 1024 + k0 + kc * 8);
    }
    __syncthreads();
    f16x8 af[4], bf[4];
#pragma unroll
    for (int tm = 0; tm < 4; ++tm)
      af[tm] = *(const f16x8*)&As[(wm * 64 + tm * 16 + mcol) * 40 + quad * 8];
#pragma unroll
    for (int tn = 0; tn < 4; ++tn)
      bf[tn] = *(const f16x8*)&Bs[(wn * 64 + tn * 16 + mcol) * 40 + quad * 8];
#pragma unroll
    for (int tm = 0; tm < 4; ++tm)
#pragma unroll
      for (int tn = 0; tn < 4; ++tn)
        acc[tm][tn] = __builtin_amdgcn_mfma_f32_16x16x32_f16(af[tm], bf[tn], acc[tm][tn], 0, 0, 0);
    __syncthreads();
  }
#pragma unroll
  for (int tm = 0; tm < 4; ++tm)
#pragma unroll
    for (int tn = 0; tn < 4; ++tn)
#pragma unroll
      for (int reg = 0; reg < 4; ++reg) {
        int row = m0 + wm * 64 + tm * 16 + quad * 4 + reg;
        int col = n0 + wn * 64 + tn * 16 + mcol;
        out[(size_t)row * 1024 + col] = acc[tm][tn][reg] + bias[col];
      }
}

extern "C" void kernel_launch(void* const* d_in, const int* in_sizes, int n_in,
                              void* d_out, int out_size, void* d_ws, size_t ws_size,
                              hipStream_t stream) {
  const float* x      = (const float*)d_in[0];
  const float* w_qkv  = (const float*)d_in[1];
  const float* w_proj = (const float*)d_in[2];
  const float* b_proj = (const float*)d_in[3];
  float* out = (float*)d_out;

  char* ws = (char*)d_ws;
  _Float16* xh   = (_Float16*)ws; ws += (size_t)M1 * C_ * 2;
  _Float16* whT  = (_Float16*)ws; ws += (size_t)3 * C_ * C_ * 2;
  _Float16* wpT  = (_Float16*)ws; ws += (size_t)C_ * C_ * 2;
  float*    qf   = (float*)ws;    ws += (size_t)BH_ * NDH * 4;
  float*    kf   = (float*)ws;    ws += (size_t)BH_ * NDH * 4;
  _Float16* vh   = (_Float16*)ws; ws += (size_t)BH_ * NDH * 2;
  char*     q8   = (char*)ws;     ws += (size_t)BH_ * NDH;
  char*     k8   = (char*)ws;     ws += (size_t)BH_ * NDH;
  _Float16* attn = (_Float16*)ws; ws += (size_t)M1 * C_ * 2;
  float*    amx  = (float*)ws;    ws += 256;

  k_cvt16<<<(M1 * C_ / 4 + 255) / 256, 256, 0, stream>>>(x, xh, M1 * C_ / 4);
  k_transmerge<<<1024, 256, 0, stream>>>(w_qkv, w_proj, whT, wpT, (unsigned*)amx);
  k_gemm_qkv<<<dim3(M1 / 128, 3 * C_ / 128), 256, 0, stream>>>(xh, whT, qf, kf, vh, (unsigned*)amx);
  k_quant<<<4096, 256, 0, stream>>>(qf, kf, amx, q8, k8);
  k_flash<<<dim3(32, 16), 256, 0, stream>>>(q8, k8, vh, amx, attn);
  k_gemm_out<<<dim3(M1 / 128, C_ / 128), 256, 0, stream>>>(attn, wpT, b_proj, out);
}

// Round 4
// 225.066 us; speedup vs baseline: 1.3745x; 1.1713x over previous
//
#include <hip/hip_runtime.h>

// Problem constants
#define B_   2
#define N_   2048
#define C_   1024
#define H_   16
#define D_   64
#define BH_  (B_*H_)      // 32
#define NDH  (N_*D_)      // 131072 elems per (b,h) plane
#define M1   (B_*N_)      // 4096 rows

typedef __attribute__((ext_vector_type(4))) float    f32x4;
typedef __attribute__((ext_vector_type(8))) _Float16 f16x8;
typedef __attribute__((ext_vector_type(4))) _Float16 f16x4;

// ---------------- fp32 -> fp16 convert ----------------
__global__ void k_cvt16(const float* __restrict__ in, _Float16* __restrict__ out, int n4) {
  int i = blockIdx.x * blockDim.x + threadIdx.x;
  if (i >= n4) return;
  float4 v = ((const float4*)in)[i];
  f16x4 o;
  o.x = (_Float16)v.x; o.y = (_Float16)v.y; o.z = (_Float16)v.z; o.w = (_Float16)v.w;
  ((f16x4*)out)[i] = o;
}

// --- merged fp32->fp16 transpose for w_qkv and w_proj (+ amax zero-init) ---
__global__ __launch_bounds__(256) void k_transmerge(const float* __restrict__ wq,
                                                    const float* __restrict__ wp,
                                                    _Float16* __restrict__ whT,
                                                    _Float16* __restrict__ wpT,
                                                    unsigned* __restrict__ amax_u) {
  if (blockIdx.x == 0 && threadIdx.x < 64) amax_u[threadIdx.x] = 0u;
  __shared__ _Float16 t[64][68];
  int idx = blockIdx.x;
  const float* in; _Float16* out; int Cc, cx, cy;
  if (idx < 768) { in = wq; out = whT; Cc = 3072; cx = idx % 48; cy = idx / 48; }
  else { idx -= 768; in = wp; out = wpT; Cc = 1024; cx = idx % 16; cy = idx / 16; }
  const int R = 1024;
  int c0 = cx * 64, r0 = cy * 64;
  int tid = threadIdx.x;
  int cq = tid & 15, rq = tid >> 4;
#pragma unroll
  for (int i = 0; i < 4; ++i) {
    int r = rq + i * 16;
    float4 v = *(const float4*)(in + (size_t)(r0 + r) * Cc + c0 + cq * 4);
    t[r][cq*4+0] = (_Float16)v.x;
    t[r][cq*4+1] = (_Float16)v.y;
    t[r][cq*4+2] = (_Float16)v.z;
    t[r][cq*4+3] = (_Float16)v.w;
  }
  __syncthreads();
#pragma unroll
  for (int i = 0; i < 4; ++i) {
    int c = rq + i * 16;
    f16x4 o;
    o.x = t[cq*4+0][c];
    o.y = t[cq*4+1][c];
    o.z = t[cq*4+2][c];
    o.w = t[cq*4+3][c];
    *(f16x4*)(out + (size_t)(c0 + c) * R + r0 + cq * 4) = o;
  }
}

// ---------------- GEMM1: qkv = x @ w_qkv, scatter epilogue + fused amax ---
// V is written in flash-fragment tiled layout: plane[c=n/32][d][kk=n%32]
__global__ __launch_bounds__(256) void k_gemm_qkv(const _Float16* __restrict__ A,
                                                  const _Float16* __restrict__ BT,
                                                  float* __restrict__ qf,
                                                  float* __restrict__ kf,
                                                  _Float16* __restrict__ vh,
                                                  unsigned* __restrict__ amax_u) {
  __shared__ __align__(16) _Float16 As[128 * 40];
  __shared__ __align__(16) _Float16 Bs[128 * 40];
  const int tid = threadIdx.x, lane = tid & 63, wave = tid >> 6;
  const int wm = wave >> 1, wn = wave & 1;
  const int mcol = lane & 15, quad = lane >> 4;
  const int m0 = blockIdx.x * 128, n0 = blockIdx.y * 128;
  f32x4 acc[4][4] = {};
  for (int k0 = 0; k0 < 1024; k0 += 32) {
#pragma unroll
    for (int r = 0; r < 2; ++r) {
      int chunk = tid + r * 256;
      int row = chunk >> 2, kc = chunk & 3;
      *(int4*)&As[row * 40 + kc * 8] = *(const int4*)(A  + (size_t)(m0 + row) * 1024 + k0 + kc * 8);
      *(int4*)&Bs[row * 40 + kc * 8] = *(const int4*)(BT + (size_t)(n0 + row) * 1024 + k0 + kc * 8);
    }
    __syncthreads();
    f16x8 af[4], bf[4];
#pragma unroll
    for (int tm = 0; tm < 4; ++tm)
      af[tm] = *(const f16x8*)&As[(wm * 64 + tm * 16 + mcol) * 40 + quad * 8];
#pragma unroll
    for (int tn = 0; tn < 4; ++tn)
      bf[tn] = *(const f16x8*)&Bs[(wn * 64 + tn * 16 + mcol) * 40 + quad * 8];
#pragma unroll
    for (int tm = 0; tm < 4; ++tm)
#pragma unroll
      for (int tn = 0; tn < 4; ++tn)
        acc[tm][tn] = __builtin_amdgcn_mfma_f32_16x16x32_f16(af[tm], bf[tn], acc[tm][tn], 0, 0, 0);
    __syncthreads();
  }
  const int sec = n0 >> 10;
  if (sec < 2) {
    float* dst = sec ? kf : qf;
    float mxv = 0.f;
#pragma unroll
    for (int tm = 0; tm < 4; ++tm)
#pragma unroll
      for (int tn = 0; tn < 4; ++tn)
#pragma unroll
        for (int reg = 0; reg < 4; ++reg) {
          int row = m0 + wm * 64 + tm * 16 + quad * 4 + reg;
          int col = n0 + wn * 64 + tn * 16 + mcol;
          int cc = col & 1023, h = cc >> 6, d = cc & 63;
          int b = row >> 11, n = row & 2047;
          float v = acc[tm][tn][reg];
          mxv = fmaxf(mxv, fabsf(v));
          dst[((size_t)(b * 16 + h) * 2048 + n) * 64 + d] = v;
        }
#pragma unroll
    for (int off = 32; off; off >>= 1) mxv = fmaxf(mxv, __shfl_xor(mxv, off));
    if (lane == 0) {
      int head = ((n0 & 1023) >> 6) + wn;
      int plane = (m0 >> 11) * 16 + head;
      atomicMax(&amax_u[sec * 32 + plane], __float_as_uint(mxv));
    }
  } else {
#pragma unroll
    for (int tm = 0; tm < 4; ++tm)
#pragma unroll
      for (int tn = 0; tn < 4; ++tn) {
        int rowb = m0 + wm * 64 + tm * 16 + quad * 4;
        int col = n0 + wn * 64 + tn * 16 + mcol;
        int cc = col & 1023, h = cc >> 6, d = cc & 63;
        int b = rowb >> 11, n = rowb & 2047;
        f16x4 o;
        o.x = (_Float16)acc[tm][tn][0];
        o.y = (_Float16)acc[tm][tn][1];
        o.z = (_Float16)acc[tm][tn][2];
        o.w = (_Float16)acc[tm][tn][3];
        // tiled: plane*131072 + (n/32)*2048 + d*32 + n%32
        *(f16x4*)&vh[(size_t)(b * 16 + h) * 131072 + (size_t)(n >> 5) * 2048 + d * 32 + (n & 31)] = o;
      }
  }
}

// ---------------- fp8 e4m3 quantize ----------------
// q8 linear [n][d]; k8 in permuted MFMA-fragment tiles:
// byte(c,e,kb,mcol,quad,j) = c*2048 + (e*2+kb)*512 + mcol*32 + quad*8 + j
// holding K[c*32 + (mcol>>2)*8 + e*4 + (mcol&3)][kb*32 + quad*8 + j]
__global__ __launch_bounds__(256) void k_quant(const float* __restrict__ qf,
                                               const float* __restrict__ kf,
                                               const float* __restrict__ amax,
                                               char* __restrict__ q8,
                                               char* __restrict__ k8) {
  int blk = blockIdx.x;
  int which = blk >> 11;
  int idx = blk & 2047;
  int bh = idx >> 6, chunk = idx & 63;
  const float* src = (which ? kf : qf) + (size_t)bh * NDH + chunk * 2048;
  float s = 448.f / fmaxf(amax[which * 32 + bh], 1e-12f);
  int t = threadIdx.x;
  float4 a = ((const float4*)(src + t * 8))[0];
  float4 c = ((const float4*)(src + t * 8))[1];
  int lo = 0, hi = 0;
  lo = __builtin_amdgcn_cvt_pk_fp8_f32(a.x * s, a.y * s, lo, false);
  lo = __builtin_amdgcn_cvt_pk_fp8_f32(a.z * s, a.w * s, lo, true);
  hi = __builtin_amdgcn_cvt_pk_fp8_f32(c.x * s, c.y * s, hi, false);
  hi = __builtin_amdgcn_cvt_pk_fp8_f32(c.z * s, c.w * s, hi, true);
  int2 o; o.x = lo; o.y = hi;
  if (which == 0) {
    char* dst = q8 + (size_t)bh * NDH + chunk * 2048;
    *(int2*)(dst + t * 8) = o;
  } else {
    int kk = t >> 3, d0 = (t & 7) * 8;          // key-in-chunk, d base
    int e = (kk >> 2) & 1;
    int mc = (kk >> 3) * 4 + (kk & 3);
    int kb = d0 >> 5, dq = (d0 >> 3) & 3;
    char* dst = k8 + (size_t)bh * NDH + chunk * 2048 + (e * 2 + kb) * 512 + mc * 32 + dq * 8;
    *(int2*)dst = o;
  }
}

// ---------------- flash causal attention (register-only, zero LDS) -------
// 4 independent waves/block. Wave handles pair {g,127-g}: 17 128-key tiles.
// S^T = K·Q^T with K rows fed in permuted order so the S^T output registers
// are exactly the PV B-operand fragment (identity k-map) -> no LDS roundtrip.
// K pre-tiled (512B coalesced frags), V pre-tiled (1KB coalesced frags).
__global__ __launch_bounds__(256, 2) void k_flash(const char* __restrict__ q8,
                                                  const char* __restrict__ k8,
                                                  const _Float16* __restrict__ vh,
                                                  const float* __restrict__ amax,
                                                  _Float16* __restrict__ attn) {
  const int bh = blockIdx.x;          // bh%8 pins K/V plane to one XCD's L2
  const int wave = threadIdx.x >> 6, lane = threadIdx.x & 63;
  const int mcol = lane & 15, quad = lane >> 4;
  const int pr = blockIdx.y * 4 + wave;     // pair index 0..63
  const int ga = pr, gb = 127 - pr;
  const int ta = (ga >> 3) + 1;             // tiles for group a; total = 17

  float sq = 448.f / fmaxf(amax[bh], 1e-12f);
  float sk = 448.f / fmaxf(amax[32 + bh], 1e-12f);
  const float c2 = (1.f / (sq * sk)) * 0.125f * 1.44269504089f;

  const size_t pbase = (size_t)bh * NDH;
  const char* kbase = k8 + pbase + mcol * 32 + quad * 8;   // lane offset in 512B frag
  const _Float16* vbase = vh + pbase + mcol * 32 + quad * 8;
  const int qrowA = ga * 16 + mcol, qrowB = gb * 16 + mcol;
  long aqA0, aqA1, aqB0, aqB1;
  { const char* qp = q8 + pbase + (size_t)qrowA * 64;
    aqA0 = *(const long*)(qp + quad * 8); aqA1 = *(const long*)(qp + 32 + quad * 8); }
  { const char* qp = q8 + pbase + (size_t)qrowB * 64;
    aqB0 = *(const long*)(qp + quad * 8); aqB1 = *(const long*)(qp + 32 + quad * 8); }

  f32x4 O[4] = {};
  float m_i = -3e38f, l_i = 0.f;
  const int b = bh >> 4, h = bh & 15;
  const int kq = quad * 8;                  // key sub-offset within 32-span

  long kc[16], kn[16];                      // [p*4 + e*2 + kb]
  {
    const char* kp = kbase;                 // tile 0, n0 = 0
#pragma unroll
    for (int i = 0; i < 16; ++i) kc[i] = *(const long*)(kp + i * 512);
  }

  auto body = [&](int t, long (&cur)[16], long (&nxt)[16]) {
    const bool inB = t >= ta;
    const int n0 = (inB ? t - ta : t) * 128;
    const long aq0 = inB ? aqB0 : aqA0;
    const long aq1 = inB ? aqB1 : aqA1;
    const int qrow = inB ? qrowB : qrowA;
    const bool last = inB ? (t == 16) : (t == ta - 1);

    // S^T: 8 frags s[p][e]; lane owns q-row = qrow
    f32x4 s[4][2];
#pragma unroll
    for (int p = 0; p < 4; ++p)
#pragma unroll
      for (int e = 0; e < 2; ++e) {
        f32x4 z = {};
        z = __builtin_amdgcn_mfma_f32_16x16x32_fp8_fp8(cur[p * 4 + e * 2 + 0], aq0, z, 0, 0, 0);
        z = __builtin_amdgcn_mfma_f32_16x16x32_fp8_fp8(cur[p * 4 + e * 2 + 1], aq1, z, 0, 0, 0);
        s[p][e] = z;
      }
    // V fragments for this tile (consumed after softmax; overlaps it)
    f16x8 va[4][4];   // [dt][p]
    {
      const _Float16* vp = vbase + (size_t)(n0 >> 5) * 2048;
#pragma unroll
      for (int p = 0; p < 4; ++p)
#pragma unroll
        for (int dt = 0; dt < 4; ++dt)
          va[dt][p] = *(const f16x8*)(vp + p * 2048 + dt * 512);
    }
    // prefetch K for tile t+1 (overlaps softmax)
    if (t < 16) {
      const int t2 = t + 1;
      const int n02 = ((t2 >= ta) ? t2 - ta : t2) * 128;
      const char* kp = kbase + (size_t)(n02 >> 5) * 2048;
#pragma unroll
      for (int i = 0; i < 16; ++i) nxt[i] = *(const long*)(kp + i * 512);
    }
    // scale + mask + tree max
    if (last) {
#pragma unroll
      for (int p = 0; p < 4; ++p)
#pragma unroll
        for (int e = 0; e < 2; ++e)
#pragma unroll
          for (int r = 0; r < 4; ++r) {
            int key = n0 + p * 32 + kq + e * 4 + r;
            float v = s[p][e][r] * c2;
            s[p][e][r] = (key <= qrow) ? v : -3e38f;
          }
    } else {
#pragma unroll
      for (int p = 0; p < 4; ++p)
#pragma unroll
        for (int e = 0; e < 2; ++e)
#pragma unroll
          for (int r = 0; r < 4; ++r)
            s[p][e][r] = s[p][e][r] * c2;
    }
    float fm[8];
#pragma unroll
    for (int p = 0; p < 4; ++p)
#pragma unroll
      for (int e = 0; e < 2; ++e) {
        f32x4 v = s[p][e];
        fm[p * 2 + e] = fmaxf(fmaxf(v[0], v[1]), fmaxf(v[2], v[3]));
      }
    float mx = fmaxf(fmaxf(fmaxf(fm[0], fm[1]), fmaxf(fm[2], fm[3])),
                     fmaxf(fmaxf(fm[4], fm[5]), fmaxf(fm[6], fm[7])));
    mx = fmaxf(mx, m_i);
    mx = fmaxf(mx, __shfl_xor(mx, 16));
    mx = fmaxf(mx, __shfl_xor(mx, 32));
    float alpha = exp2f(m_i - mx);
    m_i = mx;
    float fs[8];
#pragma unroll
    for (int p = 0; p < 4; ++p)
#pragma unroll
      for (int e = 0; e < 2; ++e) {
        float p0 = exp2f(s[p][e][0] - mx);
        float p1 = exp2f(s[p][e][1] - mx);
        float p2 = exp2f(s[p][e][2] - mx);
        float p3 = exp2f(s[p][e][3] - mx);
        s[p][e][0] = p0; s[p][e][1] = p1; s[p][e][2] = p2; s[p][e][3] = p3;
        fs[p * 2 + e] = (p0 + p1) + (p2 + p3);
      }
    float sum = ((fs[0] + fs[1]) + (fs[2] + fs[3])) + ((fs[4] + fs[5]) + (fs[6] + fs[7]));
    sum += __shfl_xor(sum, 16);
    sum += __shfl_xor(sum, 32);
    l_i = l_i * alpha + sum;
#pragma unroll
    for (int dt = 0; dt < 4; ++dt)
#pragma unroll
      for (int r = 0; r < 4; ++r)
        O[dt][r] *= alpha;
    // PV: pb is a pure register repack (identity key map)
#pragma unroll
    for (int p = 0; p < 4; ++p) {
      f16x8 pb;
      pb[0] = (_Float16)s[p][0][0]; pb[1] = (_Float16)s[p][0][1];
      pb[2] = (_Float16)s[p][0][2]; pb[3] = (_Float16)s[p][0][3];
      pb[4] = (_Float16)s[p][1][0]; pb[5] = (_Float16)s[p][1][1];
      pb[6] = (_Float16)s[p][1][2]; pb[7] = (_Float16)s[p][1][3];
#pragma unroll
      for (int dt = 0; dt < 4; ++dt)
        O[dt] = __builtin_amdgcn_mfma_f32_16x16x32_f16(va[dt][p], pb, O[dt], 0, 0, 0);
    }
    if (last) {  // emit this q-group, reset state
      float rl = 1.f / l_i;
      _Float16* op = attn + ((size_t)b * 2048 + qrow) * 1024 + h * 64;
#pragma unroll
      for (int dt = 0; dt < 4; ++dt) {
        f16x4 o;
        o.x = (_Float16)(O[dt][0] * rl);
        o.y = (_Float16)(O[dt][1] * rl);
        o.z = (_Float16)(O[dt][2] * rl);
        o.w = (_Float16)(O[dt][3] * rl);
        *(f16x4*)(op + dt * 16 + quad * 4) = o;
        O[dt] = (f32x4){0.f, 0.f, 0.f, 0.f};
      }
      m_i = -3e38f; l_i = 0.f;
    }
  };

#pragma unroll 1
  for (int t = 0; t < 17; t += 2) {
    body(t, kc, kn);
    if (t + 1 < 17) body(t + 1, kn, kc);
  }
}

// ---------------- GEMM2: out = attn @ w_proj + b ----------------
__global__ __launch_bounds__(256) void k_gemm_out(const _Float16* __restrict__ A,
                                                  const _Float16* __restrict__ BT,
                                                  const float* __restrict__ bias,
                                                  float* __restrict__ out) {
  __shared__ __align__(16) _Float16 As[128 * 40];
  __shared__ __align__(16) _Float16 Bs[128 * 40];
  const int tid = threadIdx.x, lane = tid & 63, wave = tid >> 6;
  const int wm = wave >> 1, wn = wave & 1;
  const int mcol = lane & 15, quad = lane >> 4;
  const int m0 = blockIdx.x * 128, n0 = blockIdx.y * 128;
  f32x4 acc[4][4] = {};
  for (int k0 = 0; k0 < 1024; k0 += 32) {
#pragma unroll
    for (int r = 0; r < 2; ++r) {
      int chunk = tid + r * 256;
      int row = chunk >> 2, kc = chunk & 3;
      *(int4*)&As[row * 40 + kc * 8] = *(const int4*)(A  + (size_t)(m0 + row) * 1024 + k0 + kc * 8);
      *(int4*)&Bs[row * 40 + kc * 8] = *(const int4*)(BT + (size_t)(n0 + row) * 1024 + k0 + kc * 8);
    }
    __syncthreads();
    f16x8 af[4], bf[4];
#pragma unroll
    for (int tm = 0; tm < 4; ++tm)
      af[tm] = *(const f16x8*)&As[(wm * 64 + tm * 16 + mcol) * 40 + quad * 8];
#pragma unroll
    for (int tn = 0; tn < 4; ++tn)
      bf[tn] = *(const f16x8*)&Bs[(wn * 64 + tn * 16 + mcol) * 40 + quad * 8];
#pragma unroll
    for (int tm = 0; tm < 4; ++tm)
#pragma unroll
      for (int tn = 0; tn < 4; ++tn)
        acc[tm][tn] = __builtin_amdgcn_mfma_f32_16x16x32_f16(af[tm], bf[tn], acc[tm][tn], 0, 0, 0);
    __syncthreads();
  }
#pragma unroll
  for (int tm = 0; tm < 4; ++tm)
#pragma unroll
    for (int tn = 0; tn < 4; ++tn)
#pragma unroll
      for (int reg = 0; reg < 4; ++reg) {
        int row = m0 + wm * 64 + tm * 16 + quad * 4 + reg;
        int col = n0 + wn * 64 + tn * 16 + mcol;
        out[(size_t)row * 1024 + col] = acc[tm][tn][reg] + bias[col];
      }
}

extern "C" void kernel_launch(void* const* d_in, const int* in_sizes, int n_in,
                              void* d_out, int out_size, void* d_ws, size_t ws_size,
                              hipStream_t stream) {
  const float* x      = (const float*)d_in[0];
  const float* w_qkv  = (const float*)d_in[1];
  const float* w_proj = (const float*)d_in[2];
  const float* b_proj = (const float*)d_in[3];
  float* out = (float*)d_out;

  char* ws = (char*)d_ws;
  _Float16* xh   = (_Float16*)ws; ws += (size_t)M1 * C_ * 2;
  _Float16* whT  = (_Float16*)ws; ws += (size_t)3 * C_ * C_ * 2;
  _Float16* wpT  = (_Float16*)ws; ws += (size_t)C_ * C_ * 2;
  float*    qf   = (float*)ws;    ws += (size_t)BH_ * NDH * 4;
  float*    kf   = (float*)ws;    ws += (size_t)BH_ * NDH * 4;
  _Float16* vh   = (_Float16*)ws; ws += (size_t)BH_ * NDH * 2;
  char*     q8   = (char*)ws;     ws += (size_t)BH_ * NDH;
  char*     k8   = (char*)ws;     ws += (size_t)BH_ * NDH;
  _Float16* attn = (_Float16*)ws; ws += (size_t)M1 * C_ * 2;
  float*    amx  = (float*)ws;    ws += 256;

  k_cvt16<<<(M1 * C_ / 4 + 255) / 256, 256, 0, stream>>>(x, xh, M1 * C_ / 4);
  k_transmerge<<<1024, 256, 0, stream>>>(w_qkv, w_proj, whT, wpT, (unsigned*)amx);
  k_gemm_qkv<<<dim3(M1 / 128, 3 * C_ / 128), 256, 0, stream>>>(xh, whT, qf, kf, vh, (unsigned*)amx);
  k_quant<<<4096, 256, 0, stream>>>(qf, kf, amx, q8, k8);
  k_flash<<<dim3(32, 16), 256, 0, stream>>>(q8, k8, vh, amx, attn);
  k_gemm_out<<<dim3(M1 / 128, C_ / 128), 256, 0, stream>>>(attn, wpT, b_proj, out);
}

// Round 5
// 215.364 us; speedup vs baseline: 1.4364x; 1.0451x over previous
//
#include <hip/hip_runtime.h>

// Problem constants
#define B_   2
#define N_   2048
#define C_   1024
#define H_   16
#define D_   64
#define BH_  (B_*H_)      // 32
#define NDH  (N_*D_)      // 131072 elems per (b,h) plane
#define M1   (B_*N_)      // 4096 rows

typedef __attribute__((ext_vector_type(4))) float    f32x4;
typedef __attribute__((ext_vector_type(8))) _Float16 f16x8;
typedef __attribute__((ext_vector_type(4))) _Float16 f16x4;

#define GLOAD_LDS(gp, lp) \
  __builtin_amdgcn_global_load_lds((const __attribute__((address_space(1))) void*)(gp), \
                                   (__attribute__((address_space(3))) void*)(lp), 16, 0, 0)

// ---------------- fp32 -> fp16 convert ----------------
__global__ void k_cvt16(const float* __restrict__ in, _Float16* __restrict__ out, int n4) {
  int i = blockIdx.x * blockDim.x + threadIdx.x;
  if (i >= n4) return;
  float4 v = ((const float4*)in)[i];
  f16x4 o;
  o.x = (_Float16)v.x; o.y = (_Float16)v.y; o.z = (_Float16)v.z; o.w = (_Float16)v.w;
  ((f16x4*)out)[i] = o;
}

// --- merged fp32->fp16 transpose for w_qkv and w_proj (+ amax zero-init) ---
__global__ __launch_bounds__(256) void k_transmerge(const float* __restrict__ wq,
                                                    const float* __restrict__ wp,
                                                    _Float16* __restrict__ whT,
                                                    _Float16* __restrict__ wpT,
                                                    unsigned* __restrict__ amax_u) {
  if (blockIdx.x == 0 && threadIdx.x < 64) amax_u[threadIdx.x] = 0u;
  __shared__ _Float16 t[64][68];
  int idx = blockIdx.x;
  const float* in; _Float16* out; int Cc, cx, cy;
  if (idx < 768) { in = wq; out = whT; Cc = 3072; cx = idx % 48; cy = idx / 48; }
  else { idx -= 768; in = wp; out = wpT; Cc = 1024; cx = idx % 16; cy = idx / 16; }
  const int R = 1024;
  int c0 = cx * 64, r0 = cy * 64;
  int tid = threadIdx.x;
  int cq = tid & 15, rq = tid >> 4;
#pragma unroll
  for (int i = 0; i < 4; ++i) {
    int r = rq + i * 16;
    float4 v = *(const float4*)(in + (size_t)(r0 + r) * Cc + c0 + cq * 4);
    t[r][cq*4+0] = (_Float16)v.x;
    t[r][cq*4+1] = (_Float16)v.y;
    t[r][cq*4+2] = (_Float16)v.z;
    t[r][cq*4+3] = (_Float16)v.w;
  }
  __syncthreads();
#pragma unroll
  for (int i = 0; i < 4; ++i) {
    int c = rq + i * 16;
    f16x4 o;
    o.x = t[cq*4+0][c];
    o.y = t[cq*4+1][c];
    o.z = t[cq*4+2][c];
    o.w = t[cq*4+3][c];
    *(f16x4*)(out + (size_t)(c0 + c) * R + r0 + cq * 4) = o;
  }
}

// ---------------- GEMM1: qkv = x @ w_qkv, async LDS staging --------------
// q/k stored fp16 in fragment-tiled layout plane[c=n/32][d][kk=n%32];
// v same tiled layout. amax fused (fp32 accs).
__global__ __launch_bounds__(256) void k_gemm_qkv(const _Float16* __restrict__ A,
                                                  const _Float16* __restrict__ BT,
                                                  _Float16* __restrict__ qh,
                                                  _Float16* __restrict__ kh,
                                                  _Float16* __restrict__ vh,
                                                  unsigned* __restrict__ amax_u) {
  __shared__ __align__(16) _Float16 As[128 * 32];
  __shared__ __align__(16) _Float16 Bs[128 * 32];
  const int tid = threadIdx.x, lane = tid & 63, wave = tid >> 6;
  const int wm = wave >> 1, wn = wave & 1;
  const int mcol = lane & 15, quad = lane >> 4;
  const int m0 = blockIdx.x * 128, n0 = blockIdx.y * 128;
  f32x4 acc[4][4] = {};
  for (int k0 = 0; k0 < 1024; k0 += 32) {
#pragma unroll
    for (int r = 0; r < 2; ++r) {
      int c = tid + r * 256;             // 16B chunk id; lane-contiguous LDS dest
      int row = c >> 2, kc = c & 3;
      GLOAD_LDS(A  + (size_t)(m0 + row) * 1024 + k0 + kc * 8, &As[c * 8]);
      GLOAD_LDS(BT + (size_t)(n0 + row) * 1024 + k0 + kc * 8, &Bs[c * 8]);
    }
    __syncthreads();
    f16x8 af[4], bf[4];
#pragma unroll
    for (int tm = 0; tm < 4; ++tm)
      af[tm] = *(const f16x8*)&As[(wm * 64 + tm * 16 + mcol) * 32 + quad * 8];
#pragma unroll
    for (int tn = 0; tn < 4; ++tn)
      bf[tn] = *(const f16x8*)&Bs[(wn * 64 + tn * 16 + mcol) * 32 + quad * 8];
#pragma unroll
    for (int tm = 0; tm < 4; ++tm)
#pragma unroll
      for (int tn = 0; tn < 4; ++tn)
        acc[tm][tn] = __builtin_amdgcn_mfma_f32_16x16x32_f16(af[tm], bf[tn], acc[tm][tn], 0, 0, 0);
    __syncthreads();
  }
  const int sec = n0 >> 10;
  if (sec < 2) {
    _Float16* dst = sec ? kh : qh;
    float mxv = 0.f;
#pragma unroll
    for (int tm = 0; tm < 4; ++tm)
#pragma unroll
      for (int tn = 0; tn < 4; ++tn) {
        int rowb = m0 + wm * 64 + tm * 16 + quad * 4;
        int col = n0 + wn * 64 + tn * 16 + mcol;
        int cc = col & 1023, h = cc >> 6, d = cc & 63;
        int b = rowb >> 11, n = rowb & 2047;
        f32x4 a = acc[tm][tn];
        mxv = fmaxf(mxv, fmaxf(fmaxf(fabsf(a[0]), fabsf(a[1])),
                               fmaxf(fabsf(a[2]), fabsf(a[3]))));
        f16x4 o;
        o.x = (_Float16)a[0]; o.y = (_Float16)a[1];
        o.z = (_Float16)a[2]; o.w = (_Float16)a[3];
        *(f16x4*)&dst[(size_t)(b * 16 + h) * 131072 + (size_t)(n >> 5) * 2048 + d * 32 + (n & 31)] = o;
      }
#pragma unroll
    for (int off = 32; off; off >>= 1) mxv = fmaxf(mxv, __shfl_xor(mxv, off));
    if (lane == 0) {
      int head = ((n0 & 1023) >> 6) + wn;
      int plane = (m0 >> 11) * 16 + head;
      atomicMax(&amax_u[sec * 32 + plane], __float_as_uint(mxv));
    }
  } else {
#pragma unroll
    for (int tm = 0; tm < 4; ++tm)
#pragma unroll
      for (int tn = 0; tn < 4; ++tn) {
        int rowb = m0 + wm * 64 + tm * 16 + quad * 4;
        int col = n0 + wn * 64 + tn * 16 + mcol;
        int cc = col & 1023, h = cc >> 6, d = cc & 63;
        int b = rowb >> 11, n = rowb & 2047;
        f16x4 o;
        o.x = (_Float16)acc[tm][tn][0];
        o.y = (_Float16)acc[tm][tn][1];
        o.z = (_Float16)acc[tm][tn][2];
        o.w = (_Float16)acc[tm][tn][3];
        *(f16x4*)&vh[(size_t)(b * 16 + h) * 131072 + (size_t)(n >> 5) * 2048 + d * 32 + (n & 31)] = o;
      }
  }
}

// ---------------- fp8 e4m3 quantize (tiled fp16 in, LDS transpose) -------
// q8 linear [n][d]; k8 permuted MFMA-fragment tiles (same layouts as R4).
__global__ __launch_bounds__(256) void k_quant(const _Float16* __restrict__ qh,
                                               const _Float16* __restrict__ kh,
                                               const float* __restrict__ amax,
                                               char* __restrict__ q8,
                                               char* __restrict__ k8) {
  __shared__ ushort T[32][72];   // 144B rows: 16B-aligned reads
  int blk = blockIdx.x;
  int which = blk >> 11;
  int idx = blk & 2047;
  int bh = idx >> 6, chunk = idx & 63;
  const _Float16* src = (which ? kh : qh) + (size_t)bh * NDH + chunk * 2048;
  float s = 448.f / fmaxf(amax[which * 32 + bh], 1e-12f);
  int t = threadIdx.x;
  // contiguous read: d = t>>2, kk = (t&3)*8 + j
  f16x8 v = *(const f16x8*)(src + t * 8);
  int d = t >> 2, kk0 = (t & 3) * 8;
#pragma unroll
  for (int j = 0; j < 8; ++j) T[kk0 + j][d] = ((const ushort*)&v)[j];
  __syncthreads();
  int r = t >> 3, d0 = (t & 7) * 8;
  f16x8 row = *(const f16x8*)&T[r][d0];
  float f[8];
#pragma unroll
  for (int j = 0; j < 8; ++j) f[j] = (float)((const _Float16*)&row)[j] * s;
  int lo = 0, hi = 0;
  lo = __builtin_amdgcn_cvt_pk_fp8_f32(f[0], f[1], lo, false);
  lo = __builtin_amdgcn_cvt_pk_fp8_f32(f[2], f[3], lo, true);
  hi = __builtin_amdgcn_cvt_pk_fp8_f32(f[4], f[5], hi, false);
  hi = __builtin_amdgcn_cvt_pk_fp8_f32(f[6], f[7], hi, true);
  int2 o; o.x = lo; o.y = hi;
  if (which == 0) {
    char* dst = q8 + (size_t)bh * NDH + (size_t)(chunk * 32 + r) * 64 + d0;
    *(int2*)dst = o;
  } else {
    int e = (r >> 2) & 1;
    int mc = (r >> 3) * 4 + (r & 3);
    int kb = d0 >> 5, dq = (d0 >> 3) & 3;
    char* dst = k8 + (size_t)bh * NDH + chunk * 2048 + (e * 2 + kb) * 512 + mc * 32 + dq * 8;
    *(int2*)dst = o;
  }
}

// ---------------- flash causal attention (register-only, zero LDS) -------
__global__ __launch_bounds__(256, 2) void k_flash(const char* __restrict__ q8,
                                                  const char* __restrict__ k8,
                                                  const _Float16* __restrict__ vh,
                                                  const float* __restrict__ amax,
                                                  _Float16* __restrict__ attn) {
  const int bh = blockIdx.x;
  const int wave = threadIdx.x >> 6, lane = threadIdx.x & 63;
  const int mcol = lane & 15, quad = lane >> 4;
  const int pr = blockIdx.y * 4 + wave;     // pair index 0..63
  const int ga = pr, gb = 127 - pr;
  const int ta = (ga >> 3) + 1;

  float sq = 448.f / fmaxf(amax[bh], 1e-12f);
  float sk = 448.f / fmaxf(amax[32 + bh], 1e-12f);
  const float c2 = (1.f / (sq * sk)) * 0.125f * 1.44269504089f;

  const size_t pbase = (size_t)bh * NDH;
  const char* kbase = k8 + pbase + mcol * 32 + quad * 8;
  const _Float16* vbase = vh + pbase + mcol * 32 + quad * 8;
  const int qrowA = ga * 16 + mcol, qrowB = gb * 16 + mcol;
  long aqA0, aqA1, aqB0, aqB1;
  { const char* qp = q8 + pbase + (size_t)qrowA * 64;
    aqA0 = *(const long*)(qp + quad * 8); aqA1 = *(const long*)(qp + 32 + quad * 8); }
  { const char* qp = q8 + pbase + (size_t)qrowB * 64;
    aqB0 = *(const long*)(qp + quad * 8); aqB1 = *(const long*)(qp + 32 + quad * 8); }

  f32x4 O[4] = {};
  float m_i = -3e38f, l_i = 0.f;
  const int b = bh >> 4, h = bh & 15;
  const int kq = quad * 8;

  long kc[16], kn[16];
  {
    const char* kp = kbase;
#pragma unroll
    for (int i = 0; i < 16; ++i) kc[i] = *(const long*)(kp + i * 512);
  }

  auto body = [&](int t, long (&cur)[16], long (&nxt)[16]) {
    const bool inB = t >= ta;
    const int n0 = (inB ? t - ta : t) * 128;
    const long aq0 = inB ? aqB0 : aqA0;
    const long aq1 = inB ? aqB1 : aqA1;
    const int qrow = inB ? qrowB : qrowA;
    const bool last = inB ? (t == 16) : (t == ta - 1);

    f32x4 s[4][2];
#pragma unroll
    for (int p = 0; p < 4; ++p)
#pragma unroll
      for (int e = 0; e < 2; ++e) {
        f32x4 z = {};
        z = __builtin_amdgcn_mfma_f32_16x16x32_fp8_fp8(cur[p * 4 + e * 2 + 0], aq0, z, 0, 0, 0);
        z = __builtin_amdgcn_mfma_f32_16x16x32_fp8_fp8(cur[p * 4 + e * 2 + 1], aq1, z, 0, 0, 0);
        s[p][e] = z;
      }
    f16x8 va[4][4];
    {
      const _Float16* vp = vbase + (size_t)(n0 >> 5) * 2048;
#pragma unroll
      for (int p = 0; p < 4; ++p)
#pragma unroll
        for (int dt = 0; dt < 4; ++dt)
          va[dt][p] = *(const f16x8*)(vp + p * 2048 + dt * 512);
    }
    if (t < 16) {
      const int t2 = t + 1;
      const int n02 = ((t2 >= ta) ? t2 - ta : t2) * 128;
      const char* kp = kbase + (size_t)(n02 >> 5) * 2048;
#pragma unroll
      for (int i = 0; i < 16; ++i) nxt[i] = *(const long*)(kp + i * 512);
    }
    if (last) {
#pragma unroll
      for (int p = 0; p < 4; ++p)
#pragma unroll
        for (int e = 0; e < 2; ++e)
#pragma unroll
          for (int r = 0; r < 4; ++r) {
            int key = n0 + p * 32 + kq + e * 4 + r;
            float v = s[p][e][r] * c2;
            s[p][e][r] = (key <= qrow) ? v : -3e38f;
          }
    } else {
#pragma unroll
      for (int p = 0; p < 4; ++p)
#pragma unroll
        for (int e = 0; e < 2; ++e)
#pragma unroll
          for (int r = 0; r < 4; ++r)
            s[p][e][r] = s[p][e][r] * c2;
    }
    float fm[8];
#pragma unroll
    for (int p = 0; p < 4; ++p)
#pragma unroll
      for (int e = 0; e < 2; ++e) {
        f32x4 v = s[p][e];
        fm[p * 2 + e] = fmaxf(fmaxf(v[0], v[1]), fmaxf(v[2], v[3]));
      }
    float mx = fmaxf(fmaxf(fmaxf(fm[0], fm[1]), fmaxf(fm[2], fm[3])),
                     fmaxf(fmaxf(fm[4], fm[5]), fmaxf(fm[6], fm[7])));
    mx = fmaxf(mx, m_i);
    mx = fmaxf(mx, __shfl_xor(mx, 16));
    mx = fmaxf(mx, __shfl_xor(mx, 32));
    float alpha = exp2f(m_i - mx);
    m_i = mx;
    float fs[8];
#pragma unroll
    for (int p = 0; p < 4; ++p)
#pragma unroll
      for (int e = 0; e < 2; ++e) {
        float p0 = exp2f(s[p][e][0] - mx);
        float p1 = exp2f(s[p][e][1] - mx);
        float p2 = exp2f(s[p][e][2] - mx);
        float p3 = exp2f(s[p][e][3] - mx);
        s[p][e][0] = p0; s[p][e][1] = p1; s[p][e][2] = p2; s[p][e][3] = p3;
        fs[p * 2 + e] = (p0 + p1) + (p2 + p3);
      }
    float sum = ((fs[0] + fs[1]) + (fs[2] + fs[3])) + ((fs[4] + fs[5]) + (fs[6] + fs[7]));
    sum += __shfl_xor(sum, 16);
    sum += __shfl_xor(sum, 32);
    l_i = l_i * alpha + sum;
#pragma unroll
    for (int dt = 0; dt < 4; ++dt)
#pragma unroll
      for (int r = 0; r < 4; ++r)
        O[dt][r] *= alpha;
#pragma unroll
    for (int p = 0; p < 4; ++p) {
      f16x8 pb;
      pb[0] = (_Float16)s[p][0][0]; pb[1] = (_Float16)s[p][0][1];
      pb[2] = (_Float16)s[p][0][2]; pb[3] = (_Float16)s[p][0][3];
      pb[4] = (_Float16)s[p][1][0]; pb[5] = (_Float16)s[p][1][1];
      pb[6] = (_Float16)s[p][1][2]; pb[7] = (_Float16)s[p][1][3];
#pragma unroll
      for (int dt = 0; dt < 4; ++dt)
        O[dt] = __builtin_amdgcn_mfma_f32_16x16x32_f16(va[dt][p], pb, O[dt], 0, 0, 0);
    }
    if (last) {
      float rl = 1.f / l_i;
      _Float16* op = attn + ((size_t)b * 2048 + qrow) * 1024 + h * 64;
#pragma unroll
      for (int dt = 0; dt < 4; ++dt) {
        f16x4 o;
        o.x = (_Float16)(O[dt][0] * rl);
        o.y = (_Float16)(O[dt][1] * rl);
        o.z = (_Float16)(O[dt][2] * rl);
        o.w = (_Float16)(O[dt][3] * rl);
        *(f16x4*)(op + dt * 16 + quad * 4) = o;
        O[dt] = (f32x4){0.f, 0.f, 0.f, 0.f};
      }
      m_i = -3e38f; l_i = 0.f;
    }
  };

#pragma unroll 1
  for (int t = 0; t < 17; t += 2) {
    body(t, kc, kn);
    if (t + 1 < 17) body(t + 1, kn, kc);
  }
}

// ---------------- GEMM2: out = attn @ w_proj + b (async staging) ---------
__global__ __launch_bounds__(256) void k_gemm_out(const _Float16* __restrict__ A,
                                                  const _Float16* __restrict__ BT,
                                                  const float* __restrict__ bias,
                                                  float* __restrict__ out) {
  __shared__ __align__(16) _Float16 As[128 * 32];
  __shared__ __align__(16) _Float16 Bs[128 * 32];
  const int tid = threadIdx.x, lane = tid & 63, wave = tid >> 6;
  const int wm = wave >> 1, wn = wave & 1;
  const int mcol = lane & 15, quad = lane >> 4;
  const int m0 = blockIdx.x * 128, n0 = blockIdx.y * 128;
  f32x4 acc[4][4] = {};
  for (int k0 = 0; k0 < 1024; k0 += 32) {
#pragma unroll
    for (int r = 0; r < 2; ++r) {
      int c = tid + r * 256;
      int row = c >> 2, kc = c & 3;
      GLOAD_LDS(A  + (size_t)(m0 + row) * 1024 + k0 + kc * 8, &As[c * 8]);
      GLOAD_LDS(BT + (size_t)(n0 + row) * 1024 + k0 + kc * 8, &Bs[c * 8]);
    }
    __syncthreads();
    f16x8 af[4], bf[4];
#pragma unroll
    for (int tm = 0; tm < 4; ++tm)
      af[tm] = *(const f16x8*)&As[(wm * 64 + tm * 16 + mcol) * 32 + quad * 8];
#pragma unroll
    for (int tn = 0; tn < 4; ++tn)
      bf[tn] = *(const f16x8*)&Bs[(wn * 64 + tn * 16 + mcol) * 32 + quad * 8];
#pragma unroll
    for (int tm = 0; tm < 4; ++tm)
#pragma unroll
      for (int tn = 0; tn < 4; ++tn)
        acc[tm][tn] = __builtin_amdgcn_mfma_f32_16x16x32_f16(af[tm], bf[tn], acc[tm][tn], 0, 0, 0);
    __syncthreads();
  }
#pragma unroll
  for (int tm = 0; tm < 4; ++tm)
#pragma unroll
    for (int tn = 0; tn < 4; ++tn)
#pragma unroll
      for (int reg = 0; reg < 4; ++reg) {
        int row = m0 + wm * 64 + tm * 16 + quad * 4 + reg;
        int col = n0 + wn * 64 + tn * 16 + mcol;
        out[(size_t)row * 1024 + col] = acc[tm][tn][reg] + bias[col];
      }
}

extern "C" void kernel_launch(void* const* d_in, const int* in_sizes, int n_in,
                              void* d_out, int out_size, void* d_ws, size_t ws_size,
                              hipStream_t stream) {
  const float* x      = (const float*)d_in[0];
  const float* w_qkv  = (const float*)d_in[1];
  const float* w_proj = (const float*)d_in[2];
  const float* b_proj = (const float*)d_in[3];
  float* out = (float*)d_out;

  char* ws = (char*)d_ws;
  _Float16* xh   = (_Float16*)ws; ws += (size_t)M1 * C_ * 2;
  _Float16* whT  = (_Float16*)ws; ws += (size_t)3 * C_ * C_ * 2;
  _Float16* wpT  = (_Float16*)ws; ws += (size_t)C_ * C_ * 2;
  _Float16* qh   = (_Float16*)ws; ws += (size_t)BH_ * NDH * 2;
  _Float16* kh   = (_Float16*)ws; ws += (size_t)BH_ * NDH * 2;
  _Float16* vh   = (_Float16*)ws; ws += (size_t)BH_ * NDH * 2;
  char*     q8   = (char*)ws;     ws += (size_t)BH_ * NDH;
  char*     k8   = (char*)ws;     ws += (size_t)BH_ * NDH;
  _Float16* attn = (_Float16*)ws; ws += (size_t)M1 * C_ * 2;
  float*    amx  = (float*)ws;    ws += 256;

  k_cvt16<<<(M1 * C_ / 4 + 255) / 256, 256, 0, stream>>>(x, xh, M1 * C_ / 4);
  k_transmerge<<<1024, 256, 0, stream>>>(w_qkv, w_proj, whT, wpT, (unsigned*)amx);
  k_gemm_qkv<<<dim3(M1 / 128, 3 * C_ / 128), 256, 0, stream>>>(xh, whT, qh, kh, vh, (unsigned*)amx);
  k_quant<<<4096, 256, 0, stream>>>(qh, kh, amx, q8, k8);
  k_flash<<<dim3(32, 16), 256, 0, stream>>>(q8, k8, vh, amx, attn);
  k_gemm_out<<<dim3(M1 / 128, C_ / 128), 256, 0, stream>>>(attn, wpT, b_proj, out);
}